// Round 1
// 1137.579 us; speedup vs baseline: 1.5217x; 1.5217x over previous
//
#include <hip/hip_runtime.h>

#define BB   8192
#define LEN  40
#define LDN  12
#define PQN  237
#define INN  256
#define HN   64
#define BT   32                 // batches per block (2 MFMA n-tiles of 16)
#define ENC_BLOCKS (BB / BT)    // 256 -> exactly 1 block/CU, single round
#define DW   4                  // decoder batches per block
#define DEC_BLOCKS (BB / DW)    // 2048

typedef unsigned int  u32;
typedef unsigned short u16;
typedef _Float16 f16;
typedef f16  half8 __attribute__((ext_vector_type(8)));
typedef f16  f16x4 __attribute__((ext_vector_type(4)));
typedef float f32x4 __attribute__((ext_vector_type(4)));

#define XS 264   // X row stride (f16): 132 dw -> 2-way max bank aliasing
#define HS 72    // U/H/C row stride (f16): 36 dw -> 2-way max

// weight offsets (f16 elements) in converted buffer
#define OFF_WI   0
#define OFF_WE   16384
#define OFF_VD   24576
#define OFF_WIH  40960
#define OFF_WHH  106496
#define OFF_WD   122880
#define W_TOTAL  126976

// LDS-staged embedding tables (f32): hour[24*5] wd[8*3] mon[13*4] woy[54*7]
#define T_H   0
#define T_W   120
#define T_M   144
#define T_Y   196
#define T_TOT 574

__device__ __forceinline__ float sigm(float x){
  return 1.0f / (1.0f + exp2f(-1.44269504f * x));
}
__device__ __forceinline__ float tanhf_(float x){
  x = fminf(15.0f, fmaxf(-15.0f, x));
  float e = exp2f(2.88539008f * x);
  return (e - 1.0f) / (e + 1.0f);
}

// lgkm-only barrier: LDS producer->consumer ordering WITHOUT draining vmcnt,
// so prefetch loads / mid,wmid store-acks stay in flight across phases.
// (verified pattern: learn_hip m201 8-phase template)
__device__ __forceinline__ void bar_lds(){
  asm volatile("s_waitcnt lgkmcnt(0)" ::: "memory");
  __builtin_amdgcn_s_barrier();
  asm volatile("" ::: "memory");
}

// ---------------- weight f32 -> f16 conversion (once per launch) -----------
__global__ __launch_bounds__(256) void conv_w(
    const float* __restrict__ Wi, const float* __restrict__ We,
    const float* __restrict__ Vd, const float* __restrict__ Wih,
    const float* __restrict__ Whh, const float* __restrict__ Wd,
    f16* __restrict__ dst)
{
  int i = blockIdx.x * 256 + threadIdx.x;
  if (i >= W_TOTAL) return;
  float v;
  if      (i < OFF_WE)  v = Wi [i - OFF_WI ];
  else if (i < OFF_VD)  v = We [i - OFF_WE ];
  else if (i < OFF_WIH) v = Vd [i - OFF_VD ];
  else if (i < OFF_WHH) v = Wih[i - OFF_WIH];
  else if (i < OFF_WD)  v = Whh[i - OFF_WHH];
  else                  v = Wd [i - OFF_WD ];
  dst[i] = (f16)v;
}

// ---------------- encoder: MFMA, weights register-resident -----------------
// Per 256-thread block: 32 batches = 2 MFMA n-tiles processed sequentially by
// the same 4 waves (weight regs shared).  Per step: 4 lgkm-only barriers.
//   top:    prefetched regs -> Xl; issue prefetch t+1          BAR A
//   phase2: U = tanh(Wi@X + We@[H;C] + b); wm_{t-1} = Wd@H + b BAR B
//   phase3: ee = exp(Vd@U + b); X *= ee (in place); Sred part. BAR C
//   phase4: g = Wih@P (scaled by 1/sum post-MFMA) + Whh@H;
//           LSTM update; mid store                             BAR D
//           H/C LDS writes (post-D so no wave still reads old H)
__global__ __launch_bounds__(256, 1) void enc_mfma(
    const float* __restrict__ ipq,
    const float* __restrict__ e_h, const float* __restrict__ e_w,
    const float* __restrict__ e_m, const float* __restrict__ e_y,
    const float* __restrict__ Wi_b,   // (64)
    const float* __restrict__ Vd_b,   // (256)
    const float* __restrict__ ebih, const float* __restrict__ ebhh, // (256)
    const float* __restrict__ Wd_b,   // (64)
    const f16*  __restrict__ wAll,
    const int*  __restrict__ itime,
    f16* __restrict__ mid,            // (B,LE,64)
    f16* __restrict__ wmid)           // (B,LE,64)  Wd@mid + b
{
  __shared__ __attribute__((aligned(16))) f16 Xl[BT * XS];   // X, then X*ee
  __shared__ __attribute__((aligned(16))) f16 Ul[BT * HS];
  __shared__ __attribute__((aligned(16))) f16 Hl[BT * HS];
  __shared__ __attribute__((aligned(16))) f16 Cl[BT * HS];
  __shared__ float Sred[2 * 64];
  __shared__ float Tl[T_TOT];

  const int tid  = threadIdx.x;
  const int w    = tid >> 6;
  const int lane = tid & 63;
  const int nl   = lane & 15;
  const int q    = lane >> 4;
  const int b0   = blockIdx.x * BT;
  const int d0   = w * 16 + q * 4;

  // ---- per-thread gather descriptor for x-assembly prefetch ----
  // tid < PQN: stream ipq column tid.  tid >= PQN: stream itime[...,sel] and
  // look the value up in the LDS-staged embedding table at consume time.
  const u32* pptr;
  int pstr, tstr, tbase = 0, twid = 0, tsub = 0;
  if (tid < PQN) {
    pptr = (const u32*)ipq + tid; pstr = LEN * PQN; tstr = PQN;
  } else {
    const int o = tid - PQN; int sel;
    if      (o < 5 ) { sel = 0; tbase = T_H; twid = 5; tsub = o;      }
    else if (o < 8 ) { sel = 1; tbase = T_W; twid = 3; tsub = o - 5;  }
    else if (o < 12) { sel = 2; tbase = T_M; twid = 4; tsub = o - 8;  }
    else             { sel = 3; tbase = T_Y; twid = 7; tsub = o - 12; }
    pptr = (const u32*)itime + sel; pstr = LEN * 4; tstr = 4;
  }
  pptr += (size_t)b0 * pstr;

  // ---- issue prefetch for t=0 as early as possible ----
  u32 pf[BT];
  {
    #pragma unroll
    for (int bb = 0; bb < BT; ++bb) pf[bb] = pptr[(size_t)bb * pstr];
  }

  // ---- preload weight fragments into registers (one time) ----
  half8 wif[8], wef[4], vdf[4][2], whf[4][8], whhf[4][2], wdf[2];
  {
    const f16* pw = wAll + OFF_WI + (w * 16 + nl) * 256 + q * 8;
    #pragma unroll
    for (int kt = 0; kt < 8; ++kt) wif[kt] = *(const half8*)(pw + kt * 32);
    const f16* pe = wAll + OFF_WE + (w * 16 + nl) * 128 + q * 8;
    #pragma unroll
    for (int kt = 0; kt < 4; ++kt) wef[kt] = *(const half8*)(pe + kt * 32);
    #pragma unroll
    for (int i = 0; i < 4; ++i) {
      const f16* pv = wAll + OFF_VD + ((w + 4*i) * 16 + nl) * 64 + q * 8;
      #pragma unroll
      for (int kt = 0; kt < 2; ++kt) vdf[i][kt] = *(const half8*)(pv + kt * 32);
      const f16* ph = wAll + OFF_WIH + ((w + 4*i) * 16 + nl) * 256 + q * 8;
      #pragma unroll
      for (int kt = 0; kt < 8; ++kt) whf[i][kt] = *(const half8*)(ph + kt * 32);
      const f16* pq = wAll + OFF_WHH + ((w + 4*i) * 16 + nl) * 64 + q * 8;
      #pragma unroll
      for (int kt = 0; kt < 2; ++kt) whhf[i][kt] = *(const half8*)(pq + kt * 32);
    }
    const f16* pd = wAll + OFF_WD + (w * 16 + nl) * 64 + q * 8;
    #pragma unroll
    for (int kt = 0; kt < 2; ++kt) wdf[kt] = *(const half8*)(pd + kt * 32);
  }

  float wib[4], vdb[16], ebs[16], wdb[4];
  #pragma unroll
  for (int r = 0; r < 4; ++r) { wib[r] = Wi_b[d0 + r]; wdb[r] = Wd_b[d0 + r]; }
  #pragma unroll
  for (int i = 0; i < 4; ++i)
    #pragma unroll
    for (int r = 0; r < 4; ++r) {
      vdb[i*4+r] = Vd_b[(w + 4*i) * 16 + q * 4 + r];
      ebs[i*4+r] = ebih[i * 64 + d0 + r] + ebhh[i * 64 + d0 + r];
    }

  // ---- zero H/C, stage embedding tables in LDS ----
  for (int i = tid; i < BT * HS; i += 256) { Hl[i] = (f16)0.f; Cl[i] = (f16)0.f; }
  for (int i = tid; i < T_TOT; i += 256) {
    float v;
    if      (i < T_W) v = e_h[i];
    else if (i < T_M) v = e_w[i - T_W];
    else if (i < T_Y) v = e_m[i - T_M];
    else              v = e_y[i - T_Y];
    Tl[i] = v;
  }
  float creg[2][4];
  #pragma unroll
  for (int bt = 0; bt < 2; ++bt)
    #pragma unroll
    for (int r = 0; r < 4; ++r) creg[bt][r] = 0.f;
  bar_lds();

  for (int t = 0; t < LEN; ++t) {
    // ---- top: convert prefetched regs -> Xl; reissue prefetch for t+1 ----
    #pragma unroll
    for (int bb = 0; bb < BT; ++bb) {
      float v;
      if (tid < PQN) v = __uint_as_float(pf[bb]);
      else           v = Tl[tbase + (int)pf[bb] * twid + tsub];
      Xl[bb * XS + tid] = (f16)v;
    }
    if (t + 1 < LEN) {
      const u32* pp = pptr + (size_t)(t + 1) * tstr;
      #pragma unroll
      for (int bb = 0; bb < BT; ++bb) pf[bb] = pp[(size_t)bb * pstr];
    }
    bar_lds();   // A: Xl ready; H/C of t-1 ready

    // ---- phase 2: U = tanh(Wi@X + We@[H;C] + b); wm_{t-1} = Wd@H + b ----
    #pragma unroll
    for (int bt = 0; bt < 2; ++bt) {
      const int row = bt * 16 + nl;
      f32x4 acc = {0.f, 0.f, 0.f, 0.f};
      const f16* xb = &Xl[row * XS + q * 8];
      #pragma unroll
      for (int kt = 0; kt < 8; ++kt)
        acc = __builtin_amdgcn_mfma_f32_16x16x32_f16(wif[kt], *(const half8*)(xb + kt * 32), acc, 0, 0, 0);
      const f16* hb = &Hl[row * HS + q * 8];
      const f16* cb = &Cl[row * HS + q * 8];
      half8 h0 = *(const half8*)hb, h1 = *(const half8*)(hb + 32);
      half8 c0 = *(const half8*)cb, c1 = *(const half8*)(cb + 32);
      acc = __builtin_amdgcn_mfma_f32_16x16x32_f16(wef[0], h0, acc, 0, 0, 0);
      acc = __builtin_amdgcn_mfma_f32_16x16x32_f16(wef[1], h1, acc, 0, 0, 0);
      acc = __builtin_amdgcn_mfma_f32_16x16x32_f16(wef[2], c0, acc, 0, 0, 0);
      acc = __builtin_amdgcn_mfma_f32_16x16x32_f16(wef[3], c1, acc, 0, 0, 0);
      f16x4 uv;
      #pragma unroll
      for (int r = 0; r < 4; ++r) uv[r] = (f16)tanhf_(acc[r] + wib[r]);
      *(f16x4*)(&Ul[row * HS + d0]) = uv;
      if (t > 0) {   // wm for previous step: Hl stable here, race-free
        f32x4 aw = {0.f, 0.f, 0.f, 0.f};
        aw = __builtin_amdgcn_mfma_f32_16x16x32_f16(wdf[0], h0, aw, 0, 0, 0);
        aw = __builtin_amdgcn_mfma_f32_16x16x32_f16(wdf[1], h1, aw, 0, 0, 0);
        f16x4 wv;
        #pragma unroll
        for (int r = 0; r < 4; ++r) wv[r] = (f16)(aw[r] + wdb[r]);
        *(f16x4*)(&wmid[((size_t)(b0 + row) * LEN + (t - 1)) * HN + d0]) = wv;
      }
    }
    bar_lds();   // B: Ul ready

    // ---- phase 3: ee = exp(Vd@U + b); Sred partials; X *= ee in place ----
    #pragma unroll
    for (int bt = 0; bt < 2; ++bt) {
      const int row = bt * 16 + nl;
      const f16* ub = &Ul[row * HS + q * 8];
      half8 u0 = *(const half8*)ub, u1 = *(const half8*)(ub + 32);
      float ee[16];
      #pragma unroll
      for (int i = 0; i < 4; ++i) {
        f32x4 acc = {0.f, 0.f, 0.f, 0.f};
        acc = __builtin_amdgcn_mfma_f32_16x16x32_f16(vdf[i][0], u0, acc, 0, 0, 0);
        acc = __builtin_amdgcn_mfma_f32_16x16x32_f16(vdf[i][1], u1, acc, 0, 0, 0);
        #pragma unroll
        for (int r = 0; r < 4; ++r)
          ee[i*4+r] = exp2f((acc[r] + vdb[i*4+r]) * 1.44269504f);
      }
      float s = 0.f;
      #pragma unroll
      for (int j = 0; j < 16; ++j) s += ee[j];
      s += __shfl_xor(s, 16, 64);
      s += __shfl_xor(s, 32, 64);
      if (lane < 16) Sred[bt * 64 + w * 16 + lane] = s;
      // unnormalized P stored in place (softmax scale folded in post-MFMA)
      #pragma unroll
      for (int i = 0; i < 4; ++i) {
        const int k = (w + 4*i) * 16 + q * 4;
        f16x4 xv = *(const f16x4*)(&Xl[row * XS + k]);
        f16x4 pv;
        #pragma unroll
        for (int r = 0; r < 4; ++r) pv[r] = (f16)((float)xv[r] * ee[i*4+r]);
        *(f16x4*)(&Xl[row * XS + k]) = pv;
      }
    }
    bar_lds();   // C: P + Sred ready

    // ---- phase 4: gates; scale Wih@P part by 1/sum; LSTM in registers ----
    f16x4 hstash[2], cstash[2];
    #pragma unroll
    for (int bt = 0; bt < 2; ++bt) {
      const int row = bt * 16 + nl;
      f32x4 g[4], gh[4];
      #pragma unroll
      for (int i = 0; i < 4; ++i) {
        g[i]  = (f32x4){0.f, 0.f, 0.f, 0.f};
        gh[i] = (f32x4){0.f, 0.f, 0.f, 0.f};
      }
      const f16* pb = &Xl[row * XS + q * 8];
      #pragma unroll
      for (int kt = 0; kt < 8; ++kt) {
        half8 bv = *(const half8*)(pb + kt * 32);
        #pragma unroll
        for (int i = 0; i < 4; ++i)
          g[i] = __builtin_amdgcn_mfma_f32_16x16x32_f16(whf[i][kt], bv, g[i], 0, 0, 0);
      }
      const f16* hb = &Hl[row * HS + q * 8];
      half8 h0 = *(const half8*)hb, h1 = *(const half8*)(hb + 32);
      #pragma unroll
      for (int i = 0; i < 4; ++i) {
        gh[i] = __builtin_amdgcn_mfma_f32_16x16x32_f16(whhf[i][0], h0, gh[i], 0, 0, 0);
        gh[i] = __builtin_amdgcn_mfma_f32_16x16x32_f16(whhf[i][1], h1, gh[i], 0, 0, 0);
      }
      const float inv = 1.0f / (Sred[bt*64 + nl]      + Sred[bt*64 + 16 + nl]
                              + Sred[bt*64 + 32 + nl] + Sred[bt*64 + 48 + nl]);
      f16x4 hv, cv;
      #pragma unroll
      for (int r = 0; r < 4; ++r) {
        const float gi = g[0][r] * inv + gh[0][r] + ebs[0  + r];
        const float gf = g[1][r] * inv + gh[1][r] + ebs[4  + r];
        const float gg = g[2][r] * inv + gh[2][r] + ebs[8  + r];
        const float go = g[3][r] * inv + gh[3][r] + ebs[12 + r];
        float c = sigm(gf) * creg[bt][r] + sigm(gi) * tanhf_(gg);
        creg[bt][r] = c;
        const float h = sigm(go) * tanhf_(c);
        hv[r] = (f16)h; cv[r] = (f16)c;
      }
      hstash[bt] = hv; cstash[bt] = cv;
      *(f16x4*)(&mid[((size_t)(b0 + row) * LEN + t) * HN + d0]) = hv;
    }
    bar_lds();   // D: all waves done reading P/H -> safe to overwrite H/C
    #pragma unroll
    for (int bt = 0; bt < 2; ++bt) {
      const int row = bt * 16 + nl;
      *(f16x4*)(&Hl[row * HS + d0]) = hstash[bt];
      *(f16x4*)(&Cl[row * HS + d0]) = cstash[bt];
    }
  }

  // ---- wm for final step (Hl = H_{LEN-1}) ----
  bar_lds();
  #pragma unroll
  for (int bt = 0; bt < 2; ++bt) {
    const int row = bt * 16 + nl;
    const f16* hb = &Hl[row * HS + q * 8];
    half8 h0 = *(const half8*)hb, h1 = *(const half8*)(hb + 32);
    f32x4 aw = {0.f, 0.f, 0.f, 0.f};
    aw = __builtin_amdgcn_mfma_f32_16x16x32_f16(wdf[0], h0, aw, 0, 0, 0);
    aw = __builtin_amdgcn_mfma_f32_16x16x32_f16(wdf[1], h1, aw, 0, 0, 0);
    f16x4 wv;
    #pragma unroll
    for (int r = 0; r < 4; ++r) wv[r] = (f16)(aw[r] + wdb[r]);
    *(f16x4*)(&wmid[((size_t)(b0 + row) * LEN + (LEN - 1)) * HN + d0]) = wv;
  }
}

// ---------------- decoder: 4 batches (1 wave each) per 256-thread block ----
#define MTS 56   // msT row stride (f16): d*28dw -> (7d)%8 spreads, optimal
#define WMS 56   // wm  row stride (f16): t*28dw -> (7t)%8 spreads

__global__ __launch_bounds__(256) void dec_kernel(
    const f16* __restrict__ mid,      // (B,LE,64)
    const f16* __restrict__ wmid,     // (B,LE,64)  Wd@mid + b
    const float* __restrict__ lblp,
    const float* __restrict__ Wd2_w,  // (64,2)
    const float* __restrict__ Vdt_w,  // (1,64)
    const float* __restrict__ Vdt_b,  // (1)
    const float* __restrict__ dWih,   // (4,65)
    const float* __restrict__ dWhh,   // (4,1)
    const float* __restrict__ dbih, const float* __restrict__ dbhh,
    float* __restrict__ out)          // (B,LD)
{
  __shared__ __attribute__((aligned(16))) f16  msT[DW][HN * MTS];  // [d][t]
  __shared__ __attribute__((aligned(16))) f16  wml[DW][LEN * WMS]; // [t][d]
  __shared__ __attribute__((aligned(16))) float qv[DW][HN];
  __shared__ __attribute__((aligned(16))) float Sv[DW][48];
  __shared__ __attribute__((aligned(16))) float vs[HN];

  const int w    = threadIdx.x >> 6;
  const int lane = threadIdx.x & 63;
  const int b    = blockIdx.x * DW + w;

  for (int t = 0; t < LEN; ++t) {
    msT[w][lane * MTS + t] = mid [(b * LEN + t) * HN + lane];
    wml[w][t * WMS + lane] = wmid[(b * LEN + t) * HN + lane];
  }
  if (threadIdx.x < HN) vs[threadIdx.x] = Vdt_w[threadIdx.x];
  __syncthreads();   // vs visible to all waves

  const float dpin = lblp[b * LEN + (LEN - 1)];
  const float w20 = Wd2_w[2 * lane];
  const float w21 = Wd2_w[2 * lane + 1];
  const float vdtb = Vdt_b[0];
  float wih[4], wxx[4], whh[4], bb4[4];
  #pragma unroll
  for (int j = 0; j < 4; ++j) {
    wih[j] = dWih[j * 65 + lane];
    wxx[j] = dWih[j * 65 + 64];
    whh[j] = dWhh[j];
    bb4[j] = dbih[j] + dbhh[j];
  }

  float hi = 0.0f, ci = 0.0f;
  for (int s = 0; s < LDN; ++s) {
    qv[w][lane] = w20 * hi + w21 * ci;   // same-wave LDS RAW: compiler waits

    // ---- scores: lane = t ----
    if (lane < LEN) {
      const f16* wrow = &wml[w][lane * WMS];
      float acc = 0.f;
      #pragma unroll
      for (int k8 = 0; k8 < 8; ++k8) {
        float4 qa = *(const float4*)&qv[w][k8 * 8];
        float4 qb = *(const float4*)&qv[w][k8 * 8 + 4];
        float4 va = *(const float4*)&vs[k8 * 8];
        float4 vb = *(const float4*)&vs[k8 * 8 + 4];
        half8 wv = *(const half8*)(wrow + k8 * 8);
        acc += tanhf_(qa.x + (float)wv[0]) * va.x
             + tanhf_(qa.y + (float)wv[1]) * va.y
             + tanhf_(qa.z + (float)wv[2]) * va.z
             + tanhf_(qa.w + (float)wv[3]) * va.w
             + tanhf_(qb.x + (float)wv[4]) * vb.x
             + tanhf_(qb.y + (float)wv[5]) * vb.y
             + tanhf_(qb.z + (float)wv[6]) * vb.z
             + tanhf_(qb.w + (float)wv[7]) * vb.w;
      }
      Sv[w][lane] = acc + vdtb;
    }

    // ---- ctx: lane = d ----
    float ctx = 0.f;
    {
      const f16* mrow = &msT[w][lane * MTS];
      #pragma unroll
      for (int t8 = 0; t8 < 5; ++t8) {
        float4 sa = *(const float4*)&Sv[w][t8 * 8];
        float4 sb = *(const float4*)&Sv[w][t8 * 8 + 4];
        half8 mv = *(const half8*)(mrow + t8 * 8);
        ctx += sa.x * (float)mv[0] + sa.y * (float)mv[1]
             + sa.z * (float)mv[2] + sa.w * (float)mv[3]
             + sb.x * (float)mv[4] + sb.y * (float)mv[5]
             + sb.z * (float)mv[6] + sb.w * (float)mv[7];
      }
    }

    // ---- gates: 4 full-wave reductions over d ----
    float g4[4];
    #pragma unroll
    for (int j = 0; j < 4; ++j) {
      float p = wih[j] * ctx;
      #pragma unroll
      for (int off = 32; off >= 1; off >>= 1) p += __shfl_xor(p, off, 64);
      g4[j] = p + wxx[j] * dpin + bb4[j] + whh[j] * hi;
    }
    ci = sigm(g4[1]) * ci + sigm(g4[0]) * tanhf_(g4[2]);
    hi = sigm(g4[3]) * tanhf_(ci);
    if (lane == 0) out[b * LDN + s] = hi;
  }
}

extern "C" void kernel_launch(void* const* d_in, const int* in_sizes, int n_in,
                              void* d_out, int out_size, void* d_ws, size_t ws_size,
                              hipStream_t stream) {
  (void)in_sizes; (void)n_in; (void)out_size; (void)ws_size;
  const float* ipq   = (const float*)d_in[0];
  const float* lblp  = (const float*)d_in[1];
  const float* e_h   = (const float*)d_in[2];
  const float* e_w   = (const float*)d_in[3];
  const float* e_m   = (const float*)d_in[4];
  const float* e_y   = (const float*)d_in[5];
  const float* Wi_w  = (const float*)d_in[6];
  const float* Wi_b  = (const float*)d_in[7];
  const float* We_w  = (const float*)d_in[8];
  const float* Vd_w  = (const float*)d_in[9];
  const float* Vd_b  = (const float*)d_in[10];
  const float* eWih  = (const float*)d_in[11];
  const float* eWhh  = (const float*)d_in[12];
  const float* ebih  = (const float*)d_in[13];
  const float* ebhh  = (const float*)d_in[14];
  const float* Wd_w  = (const float*)d_in[15];
  const float* Wd_b  = (const float*)d_in[16];
  const float* Wd2_w = (const float*)d_in[17];
  const float* Vdt_w = (const float*)d_in[18];
  const float* Vdt_b = (const float*)d_in[19];
  const float* dWih  = (const float*)d_in[20];
  const float* dWhh  = (const float*)d_in[21];
  const float* dbih  = (const float*)d_in[22];
  const float* dbhh  = (const float*)d_in[23];
  const int* itime   = (const int*)d_in[24];
  float* out = (float*)d_out;

  const size_t midB = (size_t)BB * LEN * HN * 2;   // 41.94 MB
  f16* mid  = (f16*)d_ws;
  f16* wmid = (f16*)((char*)d_ws + midB);
  f16* wcvt = (f16*)((char*)d_ws + 2 * midB);      // +248 KB

  conv_w<<<dim3((W_TOTAL + 255) / 256), dim3(256), 0, stream>>>(
      Wi_w, We_w, Vd_w, eWih, eWhh, Wd_w, wcvt);
  enc_mfma<<<dim3(ENC_BLOCKS), dim3(256), 0, stream>>>(
      ipq, e_h, e_w, e_m, e_y, Wi_b, Vd_b, ebih, ebhh, Wd_b, wcvt, itime,
      mid, wmid);
  dec_kernel<<<dim3(DEC_BLOCKS), dim3(256), 0, stream>>>(
      mid, wmid, lblp, Wd2_w, Vdt_w, Vdt_b, dWih, dWhh, dbih, dbhh, out);
}

// Round 2
// 938.999 us; speedup vs baseline: 1.8435x; 1.2115x over previous
//
#include <hip/hip_runtime.h>

#define BB   8192
#define LEN  40
#define LDN  12
#define PQN  237
#define INN  256
#define HN   64
#define BT   32                 // encoder batches per block (2 MFMA n-tiles)
#define ENC_BLOCKS (BB / BT)    // 256 -> 1 block/CU, single round
#define DW   8                  // decoder batches per block (1 wave each)
#define DEC_BLOCKS (BB / DW)    // 1024
#define XPS  256                // xpre row stride in f16 (power of 2)

typedef unsigned int  u32;
typedef _Float16 f16;
typedef f16  half8 __attribute__((ext_vector_type(8)));
typedef f16  f16x4 __attribute__((ext_vector_type(4)));
typedef float f32x4 __attribute__((ext_vector_type(4)));

#define XS 264   // X/P LDS row stride (f16): reads 2-way max bank aliasing
#define HS 72    // U/H/C LDS row stride (f16): 2-way max

// weight offsets (f16 elements) in converted buffer
#define OFF_WI   0
#define OFF_WE   16384
#define OFF_VD   24576
#define OFF_WIH  40960
#define OFF_WHH  106496
#define OFF_WD   122880
#define W_TOTAL  126976

// LDS-staged embedding tables (f32) for fallback encoder
#define T_H   0
#define T_W   120
#define T_M   144
#define T_Y   196
#define T_TOT 574

__device__ __forceinline__ float rcp_(float x){
#if __has_builtin(__builtin_amdgcn_rcpf)
  return __builtin_amdgcn_rcpf(x);
#else
  return 1.0f / x;
#endif
}
__device__ __forceinline__ float sigm(float x){
  return rcp_(1.0f + exp2f(-1.44269504f * x));
}
__device__ __forceinline__ float tanhf_(float x){
  x = fminf(15.0f, fmaxf(-15.0f, x));
  float e = exp2f(2.88539008f * x);
  return (e - 1.0f) * rcp_(e + 1.0f);
}

// lgkm-only barrier: LDS producer->consumer ordering WITHOUT draining vmcnt,
// so prefetch loads / mid,wmid store-acks stay in flight across phases.
__device__ __forceinline__ void bar_lds(){
  asm volatile("s_waitcnt lgkmcnt(0)" ::: "memory");
  __builtin_amdgcn_s_barrier();
  asm volatile("" ::: "memory");
}

// ---------------- weight f32 -> f16 conversion (once per launch) -----------
__global__ __launch_bounds__(256) void conv_w(
    const float* __restrict__ Wi, const float* __restrict__ We,
    const float* __restrict__ Vd, const float* __restrict__ Wih,
    const float* __restrict__ Whh, const float* __restrict__ Wd,
    f16* __restrict__ dst)
{
  int i = blockIdx.x * 256 + threadIdx.x;
  if (i >= W_TOTAL) return;
  float v;
  if      (i < OFF_WE)  v = Wi [i - OFF_WI ];
  else if (i < OFF_VD)  v = We [i - OFF_WE ];
  else if (i < OFF_WIH) v = Vd [i - OFF_VD ];
  else if (i < OFF_WHH) v = Wih[i - OFF_WIH];
  else if (i < OFF_WD)  v = Whh[i - OFF_WHH];
  else                  v = Wd [i - OFF_WD ];
  dst[i] = (f16)v;
}

// ---------------- prep_x: materialize X = concat(ipq, embs) as f16 ---------
// xpre layout: row (b*LEN+t), XPS=256 f16 per row.  ~95us streaming kernel.
__global__ __launch_bounds__(256) void prep_x(
    const float* __restrict__ ipq,
    const float* __restrict__ e_h, const float* __restrict__ e_w,
    const float* __restrict__ e_m, const float* __restrict__ e_y,
    const int*  __restrict__ itime,
    f16* __restrict__ xpre)
{
  const int wv = threadIdx.x >> 6, l = threadIdx.x & 63;
  const size_t row0 = (size_t)blockIdx.x * 32 + (size_t)wv * 8;
  for (int r = 0; r < 8; ++r) {
    const size_t row = row0 + r;               // = b*LEN + t
    const float* src = ipq + row * PQN;
    const int*  it   = itime + row * 4;
    f16* dst = xpre + row * XPS;
    #pragma unroll
    for (int k = 0; k < 4; ++k) {
      const int c = k * 64 + l;
      float v;
      if (c < PQN) v = src[c];
      else {
        const int o = c - PQN;
        if      (o < 5 ) v = e_h[it[0] * 5 + o];
        else if (o < 8 ) v = e_w[it[1] * 3 + (o - 5)];
        else if (o < 12) v = e_m[it[2] * 4 + (o - 8)];
        else             v = e_y[it[3] * 7 + (o - 12)];
      }
      dst[c] = (f16)v;
    }
  }
}

// ---------------- encoder v2: staged from xpre, mid/wmid overlay -----------
// Per step: top = 4 ds_write_b128 (staged regs) + 4 prefetch loads; then the
// proven 4-phase MFMA schedule.  mid (cols 0..63) and wmid (cols 64..127) are
// written back INTO xpre rows already consumed (row t read at step t-1).
__global__ __launch_bounds__(256, 1) void enc_x(
    const f16* __restrict__ xpre,
    const float* __restrict__ Wi_b,   // (64)
    const float* __restrict__ Vd_b,   // (256)
    const float* __restrict__ ebih, const float* __restrict__ ebhh, // (256)
    const float* __restrict__ Wd_b,   // (64)
    const f16*  __restrict__ wAll,
    f16* __restrict__ xout)           // == xpre (overlay)
{
  __shared__ __attribute__((aligned(16))) f16 Xl[BT * XS];   // X, then X*ee
  __shared__ __attribute__((aligned(16))) f16 Ul[BT * HS];
  __shared__ __attribute__((aligned(16))) f16 Hl[BT * HS];
  __shared__ __attribute__((aligned(16))) f16 Cl[BT * HS];
  __shared__ float Sred[2 * 64];

  const int tid  = threadIdx.x;
  const int w    = tid >> 6;
  const int lane = tid & 63;
  const int nl   = lane & 15;
  const int q    = lane >> 4;
  const int b0   = blockIdx.x * BT;
  const int d0   = w * 16 + q * 4;

  // staging map: chunk c = tid + j*256 -> row = (tid>>5)+8j, off = tid&31
  const int r0  = tid >> 5;
  const int off = tid & 31;
  const f16* gb = xpre + ((size_t)(b0 + r0) * LEN) * XPS + off * 8;
  const u32 lw0 = (u32)(r0 * XS + off * 8);

  // ---- issue t=0 staging loads first (longest latency headroom) ----
  half8 sr[4];
  #pragma unroll
  for (int j = 0; j < 4; ++j)
    sr[j] = *(const half8*)(gb + (size_t)(8 * j) * LEN * XPS);

  // ---- preload weight fragments into registers (one time) ----
  half8 wif[8], wef[4], vdf[4][2], whf[4][8], whhf[4][2], wdf[2];
  {
    const f16* pw = wAll + OFF_WI + (w * 16 + nl) * 256 + q * 8;
    #pragma unroll
    for (int kt = 0; kt < 8; ++kt) wif[kt] = *(const half8*)(pw + kt * 32);
    const f16* pe = wAll + OFF_WE + (w * 16 + nl) * 128 + q * 8;
    #pragma unroll
    for (int kt = 0; kt < 4; ++kt) wef[kt] = *(const half8*)(pe + kt * 32);
    #pragma unroll
    for (int i = 0; i < 4; ++i) {
      const f16* pv = wAll + OFF_VD + ((w + 4*i) * 16 + nl) * 64 + q * 8;
      #pragma unroll
      for (int kt = 0; kt < 2; ++kt) vdf[i][kt] = *(const half8*)(pv + kt * 32);
      const f16* ph = wAll + OFF_WIH + ((w + 4*i) * 16 + nl) * 256 + q * 8;
      #pragma unroll
      for (int kt = 0; kt < 8; ++kt) whf[i][kt] = *(const half8*)(ph + kt * 32);
      const f16* pq = wAll + OFF_WHH + ((w + 4*i) * 16 + nl) * 64 + q * 8;
      #pragma unroll
      for (int kt = 0; kt < 2; ++kt) whhf[i][kt] = *(const half8*)(pq + kt * 32);
    }
    const f16* pd = wAll + OFF_WD + (w * 16 + nl) * 64 + q * 8;
    #pragma unroll
    for (int kt = 0; kt < 2; ++kt) wdf[kt] = *(const half8*)(pd + kt * 32);
  }

  float wib[4], vdb[16], ebs[16], wdb[4];
  #pragma unroll
  for (int r = 0; r < 4; ++r) { wib[r] = Wi_b[d0 + r]; wdb[r] = Wd_b[d0 + r]; }
  #pragma unroll
  for (int i = 0; i < 4; ++i)
    #pragma unroll
    for (int r = 0; r < 4; ++r) {
      vdb[i*4+r] = Vd_b[(w + 4*i) * 16 + q * 4 + r];
      ebs[i*4+r] = ebih[i * 64 + d0 + r] + ebhh[i * 64 + d0 + r];
    }

  for (int i = tid; i < BT * HS; i += 256) { Hl[i] = (f16)0.f; Cl[i] = (f16)0.f; }
  float creg[2][4];
  #pragma unroll
  for (int bt = 0; bt < 2; ++bt)
    #pragma unroll
    for (int r = 0; r < 4; ++r) creg[bt][r] = 0.f;
  bar_lds();

  for (int t = 0; t < LEN; ++t) {
    // ---- top: staged regs -> Xl; reissue prefetch for t+1 ----
    #pragma unroll
    for (int j = 0; j < 4; ++j)
      *(half8*)(&Xl[lw0 + j * 8 * XS]) = sr[j];
    if (t + 1 < LEN) {
      const f16* gp = gb + (size_t)(t + 1) * XPS;
      #pragma unroll
      for (int j = 0; j < 4; ++j)
        sr[j] = *(const half8*)(gp + (size_t)(8 * j) * LEN * XPS);
    }
    bar_lds();   // A: Xl ready; H/C of t-1 ready

    // ---- phase 2: U = tanh(Wi@X + We@[H;C] + b); wm_{t-1} = Wd@H + b ----
    #pragma unroll
    for (int bt = 0; bt < 2; ++bt) {
      const int row = bt * 16 + nl;
      f32x4 acc = {0.f, 0.f, 0.f, 0.f};
      const f16* xb = &Xl[row * XS + q * 8];
      #pragma unroll
      for (int kt = 0; kt < 8; ++kt)
        acc = __builtin_amdgcn_mfma_f32_16x16x32_f16(wif[kt], *(const half8*)(xb + kt * 32), acc, 0, 0, 0);
      const f16* hb = &Hl[row * HS + q * 8];
      const f16* cb = &Cl[row * HS + q * 8];
      half8 h0 = *(const half8*)hb, h1 = *(const half8*)(hb + 32);
      half8 c0 = *(const half8*)cb, c1 = *(const half8*)(cb + 32);
      acc = __builtin_amdgcn_mfma_f32_16x16x32_f16(wef[0], h0, acc, 0, 0, 0);
      acc = __builtin_amdgcn_mfma_f32_16x16x32_f16(wef[1], h1, acc, 0, 0, 0);
      acc = __builtin_amdgcn_mfma_f32_16x16x32_f16(wef[2], c0, acc, 0, 0, 0);
      acc = __builtin_amdgcn_mfma_f32_16x16x32_f16(wef[3], c1, acc, 0, 0, 0);
      f16x4 uv;
      #pragma unroll
      for (int r = 0; r < 4; ++r) uv[r] = (f16)tanhf_(acc[r] + wib[r]);
      *(f16x4*)(&Ul[row * HS + d0]) = uv;
      if (t > 0) {   // wm for previous step: Hl stable here, race-free
        f32x4 aw = {0.f, 0.f, 0.f, 0.f};
        aw = __builtin_amdgcn_mfma_f32_16x16x32_f16(wdf[0], h0, aw, 0, 0, 0);
        aw = __builtin_amdgcn_mfma_f32_16x16x32_f16(wdf[1], h1, aw, 0, 0, 0);
        f16x4 wv;
        #pragma unroll
        for (int r = 0; r < 4; ++r) wv[r] = (f16)(aw[r] + wdb[r]);
        *(f16x4*)(&xout[((size_t)(b0 + row) * LEN + (t - 1)) * XPS + 64 + d0]) = wv;
      }
    }
    bar_lds();   // B: Ul ready

    // ---- phase 3: ee = exp(Vd@U + b); Sred partials; X *= ee in place ----
    #pragma unroll
    for (int bt = 0; bt < 2; ++bt) {
      const int row = bt * 16 + nl;
      const f16* ub = &Ul[row * HS + q * 8];
      half8 u0 = *(const half8*)ub, u1 = *(const half8*)(ub + 32);
      float ee[16];
      #pragma unroll
      for (int i = 0; i < 4; ++i) {
        f32x4 acc = {0.f, 0.f, 0.f, 0.f};
        acc = __builtin_amdgcn_mfma_f32_16x16x32_f16(vdf[i][0], u0, acc, 0, 0, 0);
        acc = __builtin_amdgcn_mfma_f32_16x16x32_f16(vdf[i][1], u1, acc, 0, 0, 0);
        #pragma unroll
        for (int r = 0; r < 4; ++r)
          ee[i*4+r] = exp2f((acc[r] + vdb[i*4+r]) * 1.44269504f);
      }
      float s = 0.f;
      #pragma unroll
      for (int j = 0; j < 16; ++j) s += ee[j];
      s += __shfl_xor(s, 16, 64);
      s += __shfl_xor(s, 32, 64);
      if (lane < 16) Sred[bt * 64 + w * 16 + lane] = s;
      #pragma unroll
      for (int i = 0; i < 4; ++i) {
        const int k = (w + 4*i) * 16 + q * 4;
        f16x4 xv = *(const f16x4*)(&Xl[row * XS + k]);
        f16x4 pv;
        #pragma unroll
        for (int r = 0; r < 4; ++r) pv[r] = (f16)((float)xv[r] * ee[i*4+r]);
        *(f16x4*)(&Xl[row * XS + k]) = pv;
      }
    }
    bar_lds();   // C: P + Sred ready

    // ---- phase 4: gates; scale Wih@P part by 1/sum; LSTM in registers ----
    f16x4 hstash[2], cstash[2];
    #pragma unroll
    for (int bt = 0; bt < 2; ++bt) {
      const int row = bt * 16 + nl;
      f32x4 g[4], gh[4];
      #pragma unroll
      for (int i = 0; i < 4; ++i) {
        g[i]  = (f32x4){0.f, 0.f, 0.f, 0.f};
        gh[i] = (f32x4){0.f, 0.f, 0.f, 0.f};
      }
      const f16* pb = &Xl[row * XS + q * 8];
      #pragma unroll
      for (int kt = 0; kt < 8; ++kt) {
        half8 bv = *(const half8*)(pb + kt * 32);
        #pragma unroll
        for (int i = 0; i < 4; ++i)
          g[i] = __builtin_amdgcn_mfma_f32_16x16x32_f16(whf[i][kt], bv, g[i], 0, 0, 0);
      }
      const f16* hb = &Hl[row * HS + q * 8];
      half8 h0 = *(const half8*)hb, h1 = *(const half8*)(hb + 32);
      #pragma unroll
      for (int i = 0; i < 4; ++i) {
        gh[i] = __builtin_amdgcn_mfma_f32_16x16x32_f16(whhf[i][0], h0, gh[i], 0, 0, 0);
        gh[i] = __builtin_amdgcn_mfma_f32_16x16x32_f16(whhf[i][1], h1, gh[i], 0, 0, 0);
      }
      const float inv = rcp_(Sred[bt*64 + nl]      + Sred[bt*64 + 16 + nl]
                           + Sred[bt*64 + 32 + nl] + Sred[bt*64 + 48 + nl]);
      f16x4 hv, cv;
      #pragma unroll
      for (int r = 0; r < 4; ++r) {
        const float gi = g[0][r] * inv + gh[0][r] + ebs[0  + r];
        const float gf = g[1][r] * inv + gh[1][r] + ebs[4  + r];
        const float gg = g[2][r] * inv + gh[2][r] + ebs[8  + r];
        const float go = g[3][r] * inv + gh[3][r] + ebs[12 + r];
        float c = sigm(gf) * creg[bt][r] + sigm(gi) * tanhf_(gg);
        creg[bt][r] = c;
        const float h = sigm(go) * tanhf_(c);
        hv[r] = (f16)h; cv[r] = (f16)c;
      }
      hstash[bt] = hv; cstash[bt] = cv;
      *(f16x4*)(&xout[((size_t)(b0 + row) * LEN + t) * XPS + d0]) = hv;
    }
    bar_lds();   // D: all waves done reading P/H -> safe to overwrite H/C
    #pragma unroll
    for (int bt = 0; bt < 2; ++bt) {
      const int row = bt * 16 + nl;
      *(f16x4*)(&Hl[row * HS + d0]) = hstash[bt];
      *(f16x4*)(&Cl[row * HS + d0]) = cstash[bt];
    }
  }

  // ---- wm for final step (Hl = H_{LEN-1}) ----
  bar_lds();
  #pragma unroll
  for (int bt = 0; bt < 2; ++bt) {
    const int row = bt * 16 + nl;
    const f16* hb = &Hl[row * HS + q * 8];
    half8 h0 = *(const half8*)hb, h1 = *(const half8*)(hb + 32);
    f32x4 aw = {0.f, 0.f, 0.f, 0.f};
    aw = __builtin_amdgcn_mfma_f32_16x16x32_f16(wdf[0], h0, aw, 0, 0, 0);
    aw = __builtin_amdgcn_mfma_f32_16x16x32_f16(wdf[1], h1, aw, 0, 0, 0);
    f16x4 wv;
    #pragma unroll
    for (int r = 0; r < 4; ++r) wv[r] = (f16)(aw[r] + wdb[r]);
    *(f16x4*)(&xout[((size_t)(b0 + row) * LEN + (LEN - 1)) * XPS + 64 + d0]) = wv;
  }
}

// ---------------- fallback encoder (round-1, proven): used if ws small -----
__global__ __launch_bounds__(256, 1) void enc_fb(
    const float* __restrict__ ipq,
    const float* __restrict__ e_h, const float* __restrict__ e_w,
    const float* __restrict__ e_m, const float* __restrict__ e_y,
    const float* __restrict__ Wi_b, const float* __restrict__ Vd_b,
    const float* __restrict__ ebih, const float* __restrict__ ebhh,
    const float* __restrict__ Wd_b, const f16* __restrict__ wAll,
    const int*  __restrict__ itime,
    f16* __restrict__ mid, f16* __restrict__ wmid)
{
  __shared__ __attribute__((aligned(16))) f16 Xl[BT * XS];
  __shared__ __attribute__((aligned(16))) f16 Ul[BT * HS];
  __shared__ __attribute__((aligned(16))) f16 Hl[BT * HS];
  __shared__ __attribute__((aligned(16))) f16 Cl[BT * HS];
  __shared__ float Sred[2 * 64];
  __shared__ float Tl[T_TOT];

  const int tid  = threadIdx.x;
  const int w    = tid >> 6;
  const int lane = tid & 63;
  const int nl   = lane & 15;
  const int q    = lane >> 4;
  const int b0   = blockIdx.x * BT;
  const int d0   = w * 16 + q * 4;

  const u32* pptr;
  int pstr, tstr, tbase = 0, twid = 0, tsub = 0;
  if (tid < PQN) {
    pptr = (const u32*)ipq + tid; pstr = LEN * PQN; tstr = PQN;
  } else {
    const int o = tid - PQN; int sel;
    if      (o < 5 ) { sel = 0; tbase = T_H; twid = 5; tsub = o;      }
    else if (o < 8 ) { sel = 1; tbase = T_W; twid = 3; tsub = o - 5;  }
    else if (o < 12) { sel = 2; tbase = T_M; twid = 4; tsub = o - 8;  }
    else             { sel = 3; tbase = T_Y; twid = 7; tsub = o - 12; }
    pptr = (const u32*)itime + sel; pstr = LEN * 4; tstr = 4;
  }
  pptr += (size_t)b0 * pstr;

  u32 pf[BT];
  #pragma unroll
  for (int bb = 0; bb < BT; ++bb) pf[bb] = pptr[(size_t)bb * pstr];

  half8 wif[8], wef[4], vdf[4][2], whf[4][8], whhf[4][2], wdf[2];
  {
    const f16* pw = wAll + OFF_WI + (w * 16 + nl) * 256 + q * 8;
    #pragma unroll
    for (int kt = 0; kt < 8; ++kt) wif[kt] = *(const half8*)(pw + kt * 32);
    const f16* pe = wAll + OFF_WE + (w * 16 + nl) * 128 + q * 8;
    #pragma unroll
    for (int kt = 0; kt < 4; ++kt) wef[kt] = *(const half8*)(pe + kt * 32);
    #pragma unroll
    for (int i = 0; i < 4; ++i) {
      const f16* pv = wAll + OFF_VD + ((w + 4*i) * 16 + nl) * 64 + q * 8;
      #pragma unroll
      for (int kt = 0; kt < 2; ++kt) vdf[i][kt] = *(const half8*)(pv + kt * 32);
      const f16* ph = wAll + OFF_WIH + ((w + 4*i) * 16 + nl) * 256 + q * 8;
      #pragma unroll
      for (int kt = 0; kt < 8; ++kt) whf[i][kt] = *(const half8*)(ph + kt * 32);
      const f16* pq = wAll + OFF_WHH + ((w + 4*i) * 16 + nl) * 64 + q * 8;
      #pragma unroll
      for (int kt = 0; kt < 2; ++kt) whhf[i][kt] = *(const half8*)(pq + kt * 32);
    }
    const f16* pd = wAll + OFF_WD + (w * 16 + nl) * 64 + q * 8;
    #pragma unroll
    for (int kt = 0; kt < 2; ++kt) wdf[kt] = *(const half8*)(pd + kt * 32);
  }

  float wib[4], vdb[16], ebs[16], wdb[4];
  #pragma unroll
  for (int r = 0; r < 4; ++r) { wib[r] = Wi_b[d0 + r]; wdb[r] = Wd_b[d0 + r]; }
  #pragma unroll
  for (int i = 0; i < 4; ++i)
    #pragma unroll
    for (int r = 0; r < 4; ++r) {
      vdb[i*4+r] = Vd_b[(w + 4*i) * 16 + q * 4 + r];
      ebs[i*4+r] = ebih[i * 64 + d0 + r] + ebhh[i * 64 + d0 + r];
    }

  for (int i = tid; i < BT * HS; i += 256) { Hl[i] = (f16)0.f; Cl[i] = (f16)0.f; }
  for (int i = tid; i < T_TOT; i += 256) {
    float v;
    if      (i < T_W) v = e_h[i];
    else if (i < T_M) v = e_w[i - T_W];
    else if (i < T_Y) v = e_m[i - T_M];
    else              v = e_y[i - T_Y];
    Tl[i] = v;
  }
  float creg[2][4];
  #pragma unroll
  for (int bt = 0; bt < 2; ++bt)
    #pragma unroll
    for (int r = 0; r < 4; ++r) creg[bt][r] = 0.f;
  bar_lds();

  for (int t = 0; t < LEN; ++t) {
    #pragma unroll
    for (int bb = 0; bb < BT; ++bb) {
      float v;
      if (tid < PQN) v = __uint_as_float(pf[bb]);
      else           v = Tl[tbase + (int)pf[bb] * twid + tsub];
      Xl[bb * XS + tid] = (f16)v;
    }
    if (t + 1 < LEN) {
      const u32* pp = pptr + (size_t)(t + 1) * tstr;
      #pragma unroll
      for (int bb = 0; bb < BT; ++bb) pf[bb] = pp[(size_t)bb * pstr];
    }
    bar_lds();

    #pragma unroll
    for (int bt = 0; bt < 2; ++bt) {
      const int row = bt * 16 + nl;
      f32x4 acc = {0.f, 0.f, 0.f, 0.f};
      const f16* xb = &Xl[row * XS + q * 8];
      #pragma unroll
      for (int kt = 0; kt < 8; ++kt)
        acc = __builtin_amdgcn_mfma_f32_16x16x32_f16(wif[kt], *(const half8*)(xb + kt * 32), acc, 0, 0, 0);
      const f16* hb = &Hl[row * HS + q * 8];
      const f16* cb = &Cl[row * HS + q * 8];
      half8 h0 = *(const half8*)hb, h1 = *(const half8*)(hb + 32);
      half8 c0 = *(const half8*)cb, c1 = *(const half8*)(cb + 32);
      acc = __builtin_amdgcn_mfma_f32_16x16x32_f16(wef[0], h0, acc, 0, 0, 0);
      acc = __builtin_amdgcn_mfma_f32_16x16x32_f16(wef[1], h1, acc, 0, 0, 0);
      acc = __builtin_amdgcn_mfma_f32_16x16x32_f16(wef[2], c0, acc, 0, 0, 0);
      acc = __builtin_amdgcn_mfma_f32_16x16x32_f16(wef[3], c1, acc, 0, 0, 0);
      f16x4 uv;
      #pragma unroll
      for (int r = 0; r < 4; ++r) uv[r] = (f16)tanhf_(acc[r] + wib[r]);
      *(f16x4*)(&Ul[row * HS + d0]) = uv;
      if (t > 0) {
        f32x4 aw = {0.f, 0.f, 0.f, 0.f};
        aw = __builtin_amdgcn_mfma_f32_16x16x32_f16(wdf[0], h0, aw, 0, 0, 0);
        aw = __builtin_amdgcn_mfma_f32_16x16x32_f16(wdf[1], h1, aw, 0, 0, 0);
        f16x4 wv;
        #pragma unroll
        for (int r = 0; r < 4; ++r) wv[r] = (f16)(aw[r] + wdb[r]);
        *(f16x4*)(&wmid[((size_t)(b0 + row) * LEN + (t - 1)) * HN + d0]) = wv;
      }
    }
    bar_lds();

    #pragma unroll
    for (int bt = 0; bt < 2; ++bt) {
      const int row = bt * 16 + nl;
      const f16* ub = &Ul[row * HS + q * 8];
      half8 u0 = *(const half8*)ub, u1 = *(const half8*)(ub + 32);
      float ee[16];
      #pragma unroll
      for (int i = 0; i < 4; ++i) {
        f32x4 acc = {0.f, 0.f, 0.f, 0.f};
        acc = __builtin_amdgcn_mfma_f32_16x16x32_f16(vdf[i][0], u0, acc, 0, 0, 0);
        acc = __builtin_amdgcn_mfma_f32_16x16x32_f16(vdf[i][1], u1, acc, 0, 0, 0);
        #pragma unroll
        for (int r = 0; r < 4; ++r)
          ee[i*4+r] = exp2f((acc[r] + vdb[i*4+r]) * 1.44269504f);
      }
      float s = 0.f;
      #pragma unroll
      for (int j = 0; j < 16; ++j) s += ee[j];
      s += __shfl_xor(s, 16, 64);
      s += __shfl_xor(s, 32, 64);
      if (lane < 16) Sred[bt * 64 + w * 16 + lane] = s;
      #pragma unroll
      for (int i = 0; i < 4; ++i) {
        const int k = (w + 4*i) * 16 + q * 4;
        f16x4 xv = *(const f16x4*)(&Xl[row * XS + k]);
        f16x4 pv;
        #pragma unroll
        for (int r = 0; r < 4; ++r) pv[r] = (f16)((float)xv[r] * ee[i*4+r]);
        *(f16x4*)(&Xl[row * XS + k]) = pv;
      }
    }
    bar_lds();

    f16x4 hstash[2], cstash[2];
    #pragma unroll
    for (int bt = 0; bt < 2; ++bt) {
      const int row = bt * 16 + nl;
      f32x4 g[4], gh[4];
      #pragma unroll
      for (int i = 0; i < 4; ++i) {
        g[i]  = (f32x4){0.f, 0.f, 0.f, 0.f};
        gh[i] = (f32x4){0.f, 0.f, 0.f, 0.f};
      }
      const f16* pb = &Xl[row * XS + q * 8];
      #pragma unroll
      for (int kt = 0; kt < 8; ++kt) {
        half8 bv = *(const half8*)(pb + kt * 32);
        #pragma unroll
        for (int i = 0; i < 4; ++i)
          g[i] = __builtin_amdgcn_mfma_f32_16x16x32_f16(whf[i][kt], bv, g[i], 0, 0, 0);
      }
      const f16* hb = &Hl[row * HS + q * 8];
      half8 h0 = *(const half8*)hb, h1 = *(const half8*)(hb + 32);
      #pragma unroll
      for (int i = 0; i < 4; ++i) {
        gh[i] = __builtin_amdgcn_mfma_f32_16x16x32_f16(whhf[i][0], h0, gh[i], 0, 0, 0);
        gh[i] = __builtin_amdgcn_mfma_f32_16x16x32_f16(whhf[i][1], h1, gh[i], 0, 0, 0);
      }
      const float inv = rcp_(Sred[bt*64 + nl]      + Sred[bt*64 + 16 + nl]
                           + Sred[bt*64 + 32 + nl] + Sred[bt*64 + 48 + nl]);
      f16x4 hv, cv;
      #pragma unroll
      for (int r = 0; r < 4; ++r) {
        const float gi = g[0][r] * inv + gh[0][r] + ebs[0  + r];
        const float gf = g[1][r] * inv + gh[1][r] + ebs[4  + r];
        const float gg = g[2][r] * inv + gh[2][r] + ebs[8  + r];
        const float go = g[3][r] * inv + gh[3][r] + ebs[12 + r];
        float c = sigm(gf) * creg[bt][r] + sigm(gi) * tanhf_(gg);
        creg[bt][r] = c;
        const float h = sigm(go) * tanhf_(c);
        hv[r] = (f16)h; cv[r] = (f16)c;
      }
      hstash[bt] = hv; cstash[bt] = cv;
      *(f16x4*)(&mid[((size_t)(b0 + row) * LEN + t) * HN + d0]) = hv;
    }
    bar_lds();
    #pragma unroll
    for (int bt = 0; bt < 2; ++bt) {
      const int row = bt * 16 + nl;
      *(f16x4*)(&Hl[row * HS + d0]) = hstash[bt];
      *(f16x4*)(&Cl[row * HS + d0]) = cstash[bt];
    }
  }

  bar_lds();
  #pragma unroll
  for (int bt = 0; bt < 2; ++bt) {
    const int row = bt * 16 + nl;
    const f16* hb = &Hl[row * HS + q * 8];
    half8 h0 = *(const half8*)hb, h1 = *(const half8*)(hb + 32);
    f32x4 aw = {0.f, 0.f, 0.f, 0.f};
    aw = __builtin_amdgcn_mfma_f32_16x16x32_f16(wdf[0], h0, aw, 0, 0, 0);
    aw = __builtin_amdgcn_mfma_f32_16x16x32_f16(wdf[1], h1, aw, 0, 0, 0);
    f16x4 wv;
    #pragma unroll
    for (int r = 0; r < 4; ++r) wv[r] = (f16)(aw[r] + wdb[r]);
    *(f16x4*)(&wmid[((size_t)(b0 + row) * LEN + (LEN - 1)) * HN + d0]) = wv;
  }
}

// ---------------- decoder v2: M4 reassociation, 8 waves/block --------------
// gates_j = sum_t score_t * M4[t][j],  M4[t][j] = sum_d Wih[j][d]*mid[t][d]
// -> no ctx stage, no msT LDS, M4 lives in registers of lane t.
#define WMS 56   // wm LDS row stride (f16)

__global__ __launch_bounds__(512) void dec_kernel(
    const f16* __restrict__ mids,     // cols 0..63 at stride MS per (b,t)
    const f16* __restrict__ wms,      // cols 0..63 at stride MS per (b,t)
    const int MS,
    const float* __restrict__ lblp,
    const float* __restrict__ Wd2_w,  // (64,2)
    const float* __restrict__ Vdt_w,  // (1,64)
    const float* __restrict__ Vdt_b,  // (1)
    const float* __restrict__ dWih,   // (4,65)
    const float* __restrict__ dWhh,   // (4,1)
    const float* __restrict__ dbih, const float* __restrict__ dbhh,
    float* __restrict__ out)          // (B,LD)
{
  __shared__ __attribute__((aligned(16))) f16  wml[DW][LEN * WMS];
  __shared__ __attribute__((aligned(16))) float qv[DW][HN];
  __shared__ __attribute__((aligned(16))) float vs[HN];
  __shared__ __attribute__((aligned(16))) float ws4[4 * 65];

  const int w    = threadIdx.x >> 6;
  const int lane = threadIdx.x & 63;
  const int b    = blockIdx.x * DW + w;

  for (int t = 0; t < LEN; ++t)
    wml[w][t * WMS + lane] = wms[((size_t)b * LEN + t) * MS + lane];
  if (threadIdx.x < HN)      vs[threadIdx.x]  = Vdt_w[threadIdx.x];
  if (threadIdx.x < 4 * 65)  ws4[threadIdx.x] = dWih[threadIdx.x];
  __syncthreads();

  // M4 precompute in registers: lane = t
  float macc[4] = {0.f, 0.f, 0.f, 0.f};
  if (lane < LEN) {
    const f16* mrow = mids + ((size_t)b * LEN + lane) * MS;
    #pragma unroll
    for (int k8 = 0; k8 < 8; ++k8) {
      half8 mv = *(const half8*)(mrow + k8 * 8);
      #pragma unroll
      for (int e = 0; e < 8; ++e) {
        const float m = (float)mv[e];
        #pragma unroll
        for (int j = 0; j < 4; ++j) macc[j] += ws4[j * 65 + k8 * 8 + e] * m;
      }
    }
  }

  const float dpin = lblp[b * LEN + (LEN - 1)];
  const float w20 = Wd2_w[2 * lane];
  const float w21 = Wd2_w[2 * lane + 1];
  const float vdtb = Vdt_b[0];
  float wxx[4], whh4[4], bb4[4];
  #pragma unroll
  for (int j = 0; j < 4; ++j) {
    wxx[j]  = dWih[j * 65 + 64];
    whh4[j] = dWhh[j];
    bb4[j]  = dbih[j] + dbhh[j];
  }

  float hi = 0.0f, ci = 0.0f;
  for (int s = 0; s < LDN; ++s) {
    qv[w][lane] = w20 * hi + w21 * ci;   // same-wave LDS RAW: compiler waits

    float p0 = 0.f, p1 = 0.f, p2 = 0.f, p3 = 0.f;
    if (lane < LEN) {
      const f16* wrow = &wml[w][lane * WMS];
      float acc = 0.f;
      #pragma unroll
      for (int k8 = 0; k8 < 8; ++k8) {
        float4 qa = *(const float4*)&qv[w][k8 * 8];
        float4 qb = *(const float4*)&qv[w][k8 * 8 + 4];
        float4 va = *(const float4*)&vs[k8 * 8];
        float4 vb = *(const float4*)&vs[k8 * 8 + 4];
        half8 wv = *(const half8*)(wrow + k8 * 8);
        acc += tanhf_(qa.x + (float)wv[0]) * va.x
             + tanhf_(qa.y + (float)wv[1]) * va.y
             + tanhf_(qa.z + (float)wv[2]) * va.z
             + tanhf_(qa.w + (float)wv[3]) * va.w
             + tanhf_(qb.x + (float)wv[4]) * vb.x
             + tanhf_(qb.y + (float)wv[5]) * vb.y
             + tanhf_(qb.z + (float)wv[6]) * vb.z
             + tanhf_(qb.w + (float)wv[7]) * vb.w;
      }
      const float score = acc + vdtb;
      p0 = score * macc[0]; p1 = score * macc[1];
      p2 = score * macc[2]; p3 = score * macc[3];
    }
    #pragma unroll
    for (int off = 32; off >= 1; off >>= 1) {
      p0 += __shfl_xor(p0, off, 64);
      p1 += __shfl_xor(p1, off, 64);
      p2 += __shfl_xor(p2, off, 64);
      p3 += __shfl_xor(p3, off, 64);
    }
    const float g0 = p0 + wxx[0] * dpin + bb4[0] + whh4[0] * hi;
    const float g1 = p1 + wxx[1] * dpin + bb4[1] + whh4[1] * hi;
    const float g2 = p2 + wxx[2] * dpin + bb4[2] + whh4[2] * hi;
    const float g3 = p3 + wxx[3] * dpin + bb4[3] + whh4[3] * hi;
    ci = sigm(g1) * ci + sigm(g0) * tanhf_(g2);
    hi = sigm(g3) * tanhf_(ci);
    if (lane == 0) out[b * LDN + s] = hi;
  }
}

extern "C" void kernel_launch(void* const* d_in, const int* in_sizes, int n_in,
                              void* d_out, int out_size, void* d_ws, size_t ws_size,
                              hipStream_t stream) {
  (void)in_sizes; (void)n_in; (void)out_size;
  const float* ipq   = (const float*)d_in[0];
  const float* lblp  = (const float*)d_in[1];
  const float* e_h   = (const float*)d_in[2];
  const float* e_w   = (const float*)d_in[3];
  const float* e_m   = (const float*)d_in[4];
  const float* e_y   = (const float*)d_in[5];
  const float* Wi_w  = (const float*)d_in[6];
  const float* Wi_b  = (const float*)d_in[7];
  const float* We_w  = (const float*)d_in[8];
  const float* Vd_w  = (const float*)d_in[9];
  const float* Vd_b  = (const float*)d_in[10];
  const float* eWih  = (const float*)d_in[11];
  const float* eWhh  = (const float*)d_in[12];
  const float* ebih  = (const float*)d_in[13];
  const float* ebhh  = (const float*)d_in[14];
  const float* Wd_w  = (const float*)d_in[15];
  const float* Wd_b  = (const float*)d_in[16];
  const float* Wd2_w = (const float*)d_in[17];
  const float* Vdt_w = (const float*)d_in[18];
  const float* Vdt_b = (const float*)d_in[19];
  const float* dWih  = (const float*)d_in[20];
  const float* dWhh  = (const float*)d_in[21];
  const float* dbih  = (const float*)d_in[22];
  const float* dbhh  = (const float*)d_in[23];
  const int* itime   = (const int*)d_in[24];
  float* out = (float*)d_out;

  const size_t xpreB = (size_t)BB * LEN * XPS * 2;   // 167.77 MB
  const size_t wcvtB = (size_t)W_TOTAL * 2;          // 254 KB

  if (ws_size >= xpreB + wcvtB) {
    f16* xpre = (f16*)d_ws;
    f16* wcvt = (f16*)((char*)d_ws + xpreB);
    conv_w<<<dim3((W_TOTAL + 255) / 256), dim3(256), 0, stream>>>(
        Wi_w, We_w, Vd_w, eWih, eWhh, Wd_w, wcvt);
    prep_x<<<dim3(BB * LEN / 32), dim3(256), 0, stream>>>(
        ipq, e_h, e_w, e_m, e_y, itime, xpre);
    enc_x<<<dim3(ENC_BLOCKS), dim3(256), 0, stream>>>(
        xpre, Wi_b, Vd_b, ebih, ebhh, Wd_b, wcvt, xpre);
    dec_kernel<<<dim3(DEC_BLOCKS), dim3(512), 0, stream>>>(
        xpre, xpre + 64, XPS, lblp, Wd2_w, Vdt_w, Vdt_b,
        dWih, dWhh, dbih, dbhh, out);
  } else {
    const size_t midB = (size_t)BB * LEN * HN * 2;   // 41.94 MB
    f16* mid  = (f16*)d_ws;
    f16* wmid = (f16*)((char*)d_ws + midB);
    f16* wcvt = (f16*)((char*)d_ws + 2 * midB);
    conv_w<<<dim3((W_TOTAL + 255) / 256), dim3(256), 0, stream>>>(
        Wi_w, We_w, Vd_w, eWih, eWhh, Wd_w, wcvt);
    enc_fb<<<dim3(ENC_BLOCKS), dim3(256), 0, stream>>>(
        ipq, e_h, e_w, e_m, e_y, Wi_b, Vd_b, ebih, ebhh, Wd_b, wcvt, itime,
        mid, wmid);
    dec_kernel<<<dim3(DEC_BLOCKS), dim3(512), 0, stream>>>(
        mid, wmid, HN, lblp, Wd2_w, Vdt_w, Vdt_b,
        dWih, dWhh, dbih, dbhh, out);
  }
}

// Round 3
// 876.261 us; speedup vs baseline: 1.9755x; 1.0716x over previous
//
#include <hip/hip_runtime.h>

#define BB   8192
#define LEN  40
#define LDN  12
#define PQN  237
#define INN  256
#define HN   64
#define BT   32                 // encoder batches per block (2 MFMA n-tiles)
#define ENC_BLOCKS (BB / BT)    // 256 -> 1 block/CU, single round
#define DW   8                  // decoder batches per block (1 wave each)
#define DEC_BLOCKS (BB / DW)    // 1024
#define XPS  256                // xpre row stride in f16 (power of 2)

typedef unsigned int  u32;
typedef _Float16 f16;
typedef f16  half8 __attribute__((ext_vector_type(8)));
typedef f16  f16x4 __attribute__((ext_vector_type(4)));
typedef float f32x4 __attribute__((ext_vector_type(4)));

#define XS 264   // X/P LDS row stride (f16): reads 2-way max bank aliasing
#define HS 72    // U/H/C LDS row stride (f16): 2-way max

// weight offsets (f16 elements) in converted buffer
#define OFF_WI   0
#define OFF_WE   16384
#define OFF_VD   24576
#define OFF_WIH  40960
#define OFF_WHH  106496
#define OFF_WD   122880
#define W_TOTAL  126976

// LDS-staged embedding tables (f32) for fallback encoder
#define T_H   0
#define T_W   120
#define T_M   144
#define T_Y   196
#define T_TOT 574

#define PREP_BLOCKS (BB * LEN / 32)          // 10240
#define CONV_BLOCKS ((W_TOTAL + 255) / 256)  // 496

__device__ __forceinline__ float rcp_(float x){
#if __has_builtin(__builtin_amdgcn_rcpf)
  return __builtin_amdgcn_rcpf(x);
#else
  return 1.0f / x;
#endif
}
__device__ __forceinline__ float sigm(float x){
  return rcp_(1.0f + exp2f(-1.44269504f * x));
}
// tanh = 1 - 2/(e^{2x}+1); exp2 overflow/underflow saturates to +-1 cleanly,
// so no clamp needed (5 ops vs 8).
__device__ __forceinline__ float tanhf_(float x){
  float e = exp2f(2.88539008f * x);
  return 1.0f - 2.0f * rcp_(e + 1.0f);
}

// lgkm-only barrier: LDS producer->consumer ordering WITHOUT draining vmcnt,
// so prefetch loads / output store-acks stay in flight across phases.
__device__ __forceinline__ void bar_lds(){
  asm volatile("s_waitcnt lgkmcnt(0)" ::: "memory");
  __builtin_amdgcn_s_barrier();
  asm volatile("" ::: "memory");
}

// ---------------- weight f32 -> f16 conversion (fallback path) -------------
__global__ __launch_bounds__(256) void conv_w(
    const float* __restrict__ Wi, const float* __restrict__ We,
    const float* __restrict__ Vd, const float* __restrict__ Wih,
    const float* __restrict__ Whh, const float* __restrict__ Wd,
    f16* __restrict__ dst)
{
  int i = blockIdx.x * 256 + threadIdx.x;
  if (i >= W_TOTAL) return;
  float v;
  if      (i < OFF_WE)  v = Wi [i - OFF_WI ];
  else if (i < OFF_VD)  v = We [i - OFF_WE ];
  else if (i < OFF_WIH) v = Vd [i - OFF_VD ];
  else if (i < OFF_WHH) v = Wih[i - OFF_WIH];
  else if (i < OFF_WD)  v = Whh[i - OFF_WHH];
  else                  v = Wd [i - OFF_WD ];
  dst[i] = (f16)v;
}

// ---------------- prep_all: X materialization + fused weight convert -------
// blocks [0, PREP_BLOCKS): xpre rows; blocks [PREP_BLOCKS, +CONV): weights.
__global__ __launch_bounds__(256) void prep_all(
    const float* __restrict__ ipq,
    const float* __restrict__ e_h, const float* __restrict__ e_w,
    const float* __restrict__ e_m, const float* __restrict__ e_y,
    const int*  __restrict__ itime,
    f16* __restrict__ xpre,
    const float* __restrict__ Wi, const float* __restrict__ We,
    const float* __restrict__ Vd, const float* __restrict__ Wih,
    const float* __restrict__ Whh, const float* __restrict__ Wd,
    f16* __restrict__ wdst)
{
  if (blockIdx.x >= PREP_BLOCKS) {
    int i = (blockIdx.x - PREP_BLOCKS) * 256 + threadIdx.x;
    if (i >= W_TOTAL) return;
    float v;
    if      (i < OFF_WE)  v = Wi [i - OFF_WI ];
    else if (i < OFF_VD)  v = We [i - OFF_WE ];
    else if (i < OFF_WIH) v = Vd [i - OFF_VD ];
    else if (i < OFF_WHH) v = Wih[i - OFF_WIH];
    else if (i < OFF_WD)  v = Whh[i - OFF_WHH];
    else                  v = Wd [i - OFF_WD ];
    wdst[i] = (f16)v;
    return;
  }
  const int wv = threadIdx.x >> 6, l = threadIdx.x & 63;
  const size_t row0 = (size_t)blockIdx.x * 32 + (size_t)wv * 8;
  // hoist all 8 rows' time indices (kills dependent-gather serialization)
  int4 itv[8];
  #pragma unroll
  for (int r = 0; r < 8; ++r)
    itv[r] = *(const int4*)(itime + (row0 + r) * 4);
  #pragma unroll
  for (int r = 0; r < 8; ++r) {
    const size_t row = row0 + r;               // = b*LEN + t
    const float* src = ipq + row * PQN;
    f16* dst = xpre + row * XPS;
    #pragma unroll
    for (int k = 0; k < 3; ++k) {              // cols < 192: always ipq
      const int c = k * 64 + l;
      dst[c] = (f16)src[c];
    }
    {                                           // tail: ipq or embedding
      const int c = 192 + l;
      float v;
      if (c < PQN) v = src[c];
      else {
        const int o = c - PQN;
        if      (o < 5 ) v = e_h[itv[r].x * 5 + o];
        else if (o < 8 ) v = e_w[itv[r].y * 3 + (o - 5)];
        else if (o < 12) v = e_m[itv[r].z * 4 + (o - 8)];
        else             v = e_y[itv[r].w * 7 + (o - 12)];
      }
      dst[c] = (f16)v;
    }
  }
}

// ---------------- encoder v3: 3 barriers/step, coalesced outputs -----------
// Double-buffered Xl/Hl/Cl removes the trailing barrier:
//   top(t):  staged regs -> Xl[cur]; prefetch t+1                BAR A
//   ph2(t):  U = tanh(Wi@X + We@[H;C]+b); Wml = Wd@H(t-1)+b      BAR B
//   ph3(t):  stream mid/wmid(t-1) from Hl/Wml (coalesced 16B);
//            ee = exp(Vd@U+b); Sred partials; P = X*ee in place  BAR C
//   ph4(t):  gates (Wih@P scaled post-MFMA + Whh@H); LSTM;
//            H/C -> Hl[nxt]/Cl[nxt]          (no barrier; A(t+1) orders)
// Safety: any wave in top(t+1) passed C(t) => all waves finished ph4(t-1)'s
// reads of the buffers being overwritten (barriers transitively order).
__global__ __launch_bounds__(256, 1) void enc_x(
    const f16* __restrict__ xpre,
    const float* __restrict__ Wi_b,   // (64)
    const float* __restrict__ Vd_b,   // (256)
    const float* __restrict__ ebih, const float* __restrict__ ebhh, // (256)
    const float* __restrict__ Wd_b,   // (64)
    const f16*  __restrict__ wAll,
    f16* __restrict__ xout)           // == xpre (overlay)
{
  __shared__ __attribute__((aligned(16))) f16 Xl[2][BT * XS];
  __shared__ __attribute__((aligned(16))) f16 Ul[BT * HS];
  __shared__ __attribute__((aligned(16))) f16 Hl[2][BT * HS];
  __shared__ __attribute__((aligned(16))) f16 Cl[2][BT * HS];
  __shared__ __attribute__((aligned(16))) f16 Wml[BT * HS];
  __shared__ float Sred[2 * 64];

  const int tid  = threadIdx.x;
  const int w    = tid >> 6;
  const int lane = tid & 63;
  const int nl   = lane & 15;
  const int q    = lane >> 4;
  const int b0   = blockIdx.x * BT;
  const int d0   = w * 16 + q * 4;

  // staging map: thread covers row r0 = tid>>5 (+8j), 16B at off = tid&31
  const int r0  = tid >> 5;
  const int off = tid & 31;
  const f16* gb = xpre + ((size_t)(b0 + r0) * LEN) * XPS + off * 8;
  const u32 lw0 = (u32)(r0 * XS + off * 8);

  // output streaming map: thread covers (orow, oc8)
  const int orow = tid >> 3;
  const int oc8  = (tid & 7) * 8;

  // ---- issue t=0 staging loads first ----
  half8 sr[4];
  #pragma unroll
  for (int j = 0; j < 4; ++j)
    sr[j] = *(const half8*)(gb + (size_t)(8 * j) * LEN * XPS);

  // ---- preload weight fragments into registers (one time) ----
  half8 wif[8], wef[4], vdf[4][2], whf[4][8], whhf[4][2], wdf[2];
  {
    const f16* pw = wAll + OFF_WI + (w * 16 + nl) * 256 + q * 8;
    #pragma unroll
    for (int kt = 0; kt < 8; ++kt) wif[kt] = *(const half8*)(pw + kt * 32);
    const f16* pe = wAll + OFF_WE + (w * 16 + nl) * 128 + q * 8;
    #pragma unroll
    for (int kt = 0; kt < 4; ++kt) wef[kt] = *(const half8*)(pe + kt * 32);
    #pragma unroll
    for (int i = 0; i < 4; ++i) {
      const f16* pv = wAll + OFF_VD + ((w + 4*i) * 16 + nl) * 64 + q * 8;
      #pragma unroll
      for (int kt = 0; kt < 2; ++kt) vdf[i][kt] = *(const half8*)(pv + kt * 32);
      const f16* ph = wAll + OFF_WIH + ((w + 4*i) * 16 + nl) * 256 + q * 8;
      #pragma unroll
      for (int kt = 0; kt < 8; ++kt) whf[i][kt] = *(const half8*)(ph + kt * 32);
      const f16* pq = wAll + OFF_WHH + ((w + 4*i) * 16 + nl) * 64 + q * 8;
      #pragma unroll
      for (int kt = 0; kt < 2; ++kt) whhf[i][kt] = *(const half8*)(pq + kt * 32);
    }
    const f16* pd = wAll + OFF_WD + (w * 16 + nl) * 64 + q * 8;
    #pragma unroll
    for (int kt = 0; kt < 2; ++kt) wdf[kt] = *(const half8*)(pd + kt * 32);
  }

  float wib[4], vdb[16], ebs[16], wdb[4];
  #pragma unroll
  for (int r = 0; r < 4; ++r) { wib[r] = Wi_b[d0 + r]; wdb[r] = Wd_b[d0 + r]; }
  #pragma unroll
  for (int i = 0; i < 4; ++i)
    #pragma unroll
    for (int r = 0; r < 4; ++r) {
      vdb[i*4+r] = Vd_b[(w + 4*i) * 16 + q * 4 + r];
      ebs[i*4+r] = ebih[i * 64 + d0 + r] + ebhh[i * 64 + d0 + r];
    }

  for (int i = tid; i < BT * HS; i += 256) {
    Hl[0][i] = (f16)0.f; Cl[0][i] = (f16)0.f;
  }
  float creg[2][4];
  #pragma unroll
  for (int bt = 0; bt < 2; ++bt)
    #pragma unroll
    for (int r = 0; r < 4; ++r) creg[bt][r] = 0.f;
  bar_lds();

  for (int t = 0; t < LEN; ++t) {
    const int cur = t & 1, nxt = cur ^ 1;
    // ---- top: staged regs -> Xl[cur]; reissue prefetch for t+1 ----
    #pragma unroll
    for (int j = 0; j < 4; ++j)
      *(half8*)(&Xl[cur][lw0 + j * 8 * XS]) = sr[j];
    if (t + 1 < LEN) {
      const f16* gp = gb + (size_t)(t + 1) * XPS;
      #pragma unroll
      for (int j = 0; j < 4; ++j)
        sr[j] = *(const half8*)(gp + (size_t)(8 * j) * LEN * XPS);
    }
    bar_lds();   // A: Xl[cur] + Hl[cur]/Cl[cur] (from ph4(t-1)) ready

    // ---- phase 2: U = tanh(Wi@X + We@[H;C] + b); Wml = Wd@H(t-1)+b ----
    #pragma unroll
    for (int bt = 0; bt < 2; ++bt) {
      const int row = bt * 16 + nl;
      f32x4 acc = {0.f, 0.f, 0.f, 0.f};
      const f16* xb = &Xl[cur][row * XS + q * 8];
      #pragma unroll
      for (int kt = 0; kt < 8; ++kt)
        acc = __builtin_amdgcn_mfma_f32_16x16x32_f16(wif[kt], *(const half8*)(xb + kt * 32), acc, 0, 0, 0);
      const f16* hb = &Hl[cur][row * HS + q * 8];
      const f16* cb = &Cl[cur][row * HS + q * 8];
      half8 h0 = *(const half8*)hb, h1 = *(const half8*)(hb + 32);
      half8 c0 = *(const half8*)cb, c1 = *(const half8*)(cb + 32);
      acc = __builtin_amdgcn_mfma_f32_16x16x32_f16(wef[0], h0, acc, 0, 0, 0);
      acc = __builtin_amdgcn_mfma_f32_16x16x32_f16(wef[1], h1, acc, 0, 0, 0);
      acc = __builtin_amdgcn_mfma_f32_16x16x32_f16(wef[2], c0, acc, 0, 0, 0);
      acc = __builtin_amdgcn_mfma_f32_16x16x32_f16(wef[3], c1, acc, 0, 0, 0);
      f16x4 uv;
      #pragma unroll
      for (int r = 0; r < 4; ++r) uv[r] = (f16)tanhf_(acc[r] + wib[r]);
      *(f16x4*)(&Ul[row * HS + d0]) = uv;
      if (t > 0) {   // wm(t-1) -> LDS (coalesced global store happens in ph3)
        f32x4 aw = {0.f, 0.f, 0.f, 0.f};
        aw = __builtin_amdgcn_mfma_f32_16x16x32_f16(wdf[0], h0, aw, 0, 0, 0);
        aw = __builtin_amdgcn_mfma_f32_16x16x32_f16(wdf[1], h1, aw, 0, 0, 0);
        f16x4 wv;
        #pragma unroll
        for (int r = 0; r < 4; ++r) wv[r] = (f16)(aw[r] + wdb[r]);
        *(f16x4*)(&Wml[row * HS + d0]) = wv;
      }
    }
    bar_lds();   // B: Ul + Wml ready

    // ---- phase 3: stream outputs(t-1); ee = exp(Vd@U+b); P = X*ee ----
    if (t > 0) {   // coalesced 16B stores: 128B contiguous per 8 threads
      half8 hv8 = *(const half8*)(&Hl[cur][orow * HS + oc8]);
      half8 wv8 = *(const half8*)(&Wml[orow * HS + oc8]);
      f16* xr = xout + ((size_t)(b0 + orow) * LEN + (t - 1)) * XPS;
      *(half8*)(xr + oc8)      = hv8;
      *(half8*)(xr + 64 + oc8) = wv8;
    }
    #pragma unroll
    for (int bt = 0; bt < 2; ++bt) {
      const int row = bt * 16 + nl;
      const f16* ub = &Ul[row * HS + q * 8];
      half8 u0 = *(const half8*)ub, u1 = *(const half8*)(ub + 32);
      float ee[16];
      #pragma unroll
      for (int i = 0; i < 4; ++i) {
        f32x4 acc = {0.f, 0.f, 0.f, 0.f};
        acc = __builtin_amdgcn_mfma_f32_16x16x32_f16(vdf[i][0], u0, acc, 0, 0, 0);
        acc = __builtin_amdgcn_mfma_f32_16x16x32_f16(vdf[i][1], u1, acc, 0, 0, 0);
        #pragma unroll
        for (int r = 0; r < 4; ++r)
          ee[i*4+r] = exp2f((acc[r] + vdb[i*4+r]) * 1.44269504f);
      }
      float s = 0.f;
      #pragma unroll
      for (int j = 0; j < 16; ++j) s += ee[j];
      s += __shfl_xor(s, 16, 64);
      s += __shfl_xor(s, 32, 64);
      if (lane < 16) Sred[bt * 64 + w * 16 + lane] = s;
      #pragma unroll
      for (int i = 0; i < 4; ++i) {
        const int k = (w + 4*i) * 16 + q * 4;
        f16x4 xv = *(const f16x4*)(&Xl[cur][row * XS + k]);
        f16x4 pv;
        #pragma unroll
        for (int r = 0; r < 4; ++r) pv[r] = (f16)((float)xv[r] * ee[i*4+r]);
        *(f16x4*)(&Xl[cur][row * XS + k]) = pv;
      }
    }
    bar_lds();   // C: P + Sred ready

    // ---- phase 4: gates; LSTM; H/C -> next buffers (no barrier) ----
    #pragma unroll
    for (int bt = 0; bt < 2; ++bt) {
      const int row = bt * 16 + nl;
      f32x4 g[4], gh[4];
      #pragma unroll
      for (int i = 0; i < 4; ++i) {
        g[i]  = (f32x4){0.f, 0.f, 0.f, 0.f};
        gh[i] = (f32x4){0.f, 0.f, 0.f, 0.f};
      }
      const f16* pb = &Xl[cur][row * XS + q * 8];
      #pragma unroll
      for (int kt = 0; kt < 8; ++kt) {
        half8 bv = *(const half8*)(pb + kt * 32);
        #pragma unroll
        for (int i = 0; i < 4; ++i)
          g[i] = __builtin_amdgcn_mfma_f32_16x16x32_f16(whf[i][kt], bv, g[i], 0, 0, 0);
      }
      const f16* hb = &Hl[cur][row * HS + q * 8];
      half8 h0 = *(const half8*)hb, h1 = *(const half8*)(hb + 32);
      #pragma unroll
      for (int i = 0; i < 4; ++i) {
        gh[i] = __builtin_amdgcn_mfma_f32_16x16x32_f16(whhf[i][0], h0, gh[i], 0, 0, 0);
        gh[i] = __builtin_amdgcn_mfma_f32_16x16x32_f16(whhf[i][1], h1, gh[i], 0, 0, 0);
      }
      const float inv = rcp_(Sred[bt*64 + nl]      + Sred[bt*64 + 16 + nl]
                           + Sred[bt*64 + 32 + nl] + Sred[bt*64 + 48 + nl]);
      f16x4 hv, cv;
      #pragma unroll
      for (int r = 0; r < 4; ++r) {
        const float gi = g[0][r] * inv + gh[0][r] + ebs[0  + r];
        const float gf = g[1][r] * inv + gh[1][r] + ebs[4  + r];
        const float gg = g[2][r] * inv + gh[2][r] + ebs[8  + r];
        const float go = g[3][r] * inv + gh[3][r] + ebs[12 + r];
        float c = sigm(gf) * creg[bt][r] + sigm(gi) * tanhf_(gg);
        creg[bt][r] = c;
        const float h = sigm(go) * tanhf_(c);
        hv[r] = (f16)h; cv[r] = (f16)c;
      }
      *(f16x4*)(&Hl[nxt][row * HS + d0]) = hv;
      *(f16x4*)(&Cl[nxt][row * HS + d0]) = cv;
    }
    // no barrier D: next top writes Xl[nxt]; barrier A(t+1) orders Hl/Cl[nxt]
  }

  // ---- epilogue: wm(LEN-1) + stream final outputs (H in Hl[LEN&1=0]) ----
  bar_lds();
  #pragma unroll
  for (int bt = 0; bt < 2; ++bt) {
    const int row = bt * 16 + nl;
    const f16* hb = &Hl[0][row * HS + q * 8];
    half8 h0 = *(const half8*)hb, h1 = *(const half8*)(hb + 32);
    f32x4 aw = {0.f, 0.f, 0.f, 0.f};
    aw = __builtin_amdgcn_mfma_f32_16x16x32_f16(wdf[0], h0, aw, 0, 0, 0);
    aw = __builtin_amdgcn_mfma_f32_16x16x32_f16(wdf[1], h1, aw, 0, 0, 0);
    f16x4 wv;
    #pragma unroll
    for (int r = 0; r < 4; ++r) wv[r] = (f16)(aw[r] + wdb[r]);
    *(f16x4*)(&Wml[row * HS + d0]) = wv;
  }
  bar_lds();
  {
    half8 hv8 = *(const half8*)(&Hl[0][orow * HS + oc8]);
    half8 wv8 = *(const half8*)(&Wml[orow * HS + oc8]);
    f16* xr = xout + ((size_t)(b0 + orow) * LEN + (LEN - 1)) * XPS;
    *(half8*)(xr + oc8)      = hv8;
    *(half8*)(xr + 64 + oc8) = wv8;
  }
}

// ---------------- fallback encoder (round-2, proven): used if ws small -----
__global__ __launch_bounds__(256, 1) void enc_fb(
    const float* __restrict__ ipq,
    const float* __restrict__ e_h, const float* __restrict__ e_w,
    const float* __restrict__ e_m, const float* __restrict__ e_y,
    const float* __restrict__ Wi_b, const float* __restrict__ Vd_b,
    const float* __restrict__ ebih, const float* __restrict__ ebhh,
    const float* __restrict__ Wd_b, const f16* __restrict__ wAll,
    const int*  __restrict__ itime,
    f16* __restrict__ mid, f16* __restrict__ wmid)
{
  __shared__ __attribute__((aligned(16))) f16 Xl[BT * XS];
  __shared__ __attribute__((aligned(16))) f16 Ul[BT * HS];
  __shared__ __attribute__((aligned(16))) f16 Hl[BT * HS];
  __shared__ __attribute__((aligned(16))) f16 Cl[BT * HS];
  __shared__ float Sred[2 * 64];
  __shared__ float Tl[T_TOT];

  const int tid  = threadIdx.x;
  const int w    = tid >> 6;
  const int lane = tid & 63;
  const int nl   = lane & 15;
  const int q    = lane >> 4;
  const int b0   = blockIdx.x * BT;
  const int d0   = w * 16 + q * 4;

  const u32* pptr;
  int pstr, tstr, tbase = 0, twid = 0, tsub = 0;
  if (tid < PQN) {
    pptr = (const u32*)ipq + tid; pstr = LEN * PQN; tstr = PQN;
  } else {
    const int o = tid - PQN; int sel;
    if      (o < 5 ) { sel = 0; tbase = T_H; twid = 5; tsub = o;      }
    else if (o < 8 ) { sel = 1; tbase = T_W; twid = 3; tsub = o - 5;  }
    else if (o < 12) { sel = 2; tbase = T_M; twid = 4; tsub = o - 8;  }
    else             { sel = 3; tbase = T_Y; twid = 7; tsub = o - 12; }
    pptr = (const u32*)itime + sel; pstr = LEN * 4; tstr = 4;
  }
  pptr += (size_t)b0 * pstr;

  u32 pf[BT];
  #pragma unroll
  for (int bb = 0; bb < BT; ++bb) pf[bb] = pptr[(size_t)bb * pstr];

  half8 wif[8], wef[4], vdf[4][2], whf[4][8], whhf[4][2], wdf[2];
  {
    const f16* pw = wAll + OFF_WI + (w * 16 + nl) * 256 + q * 8;
    #pragma unroll
    for (int kt = 0; kt < 8; ++kt) wif[kt] = *(const half8*)(pw + kt * 32);
    const f16* pe = wAll + OFF_WE + (w * 16 + nl) * 128 + q * 8;
    #pragma unroll
    for (int kt = 0; kt < 4; ++kt) wef[kt] = *(const half8*)(pe + kt * 32);
    #pragma unroll
    for (int i = 0; i < 4; ++i) {
      const f16* pv = wAll + OFF_VD + ((w + 4*i) * 16 + nl) * 64 + q * 8;
      #pragma unroll
      for (int kt = 0; kt < 2; ++kt) vdf[i][kt] = *(const half8*)(pv + kt * 32);
      const f16* ph = wAll + OFF_WIH + ((w + 4*i) * 16 + nl) * 256 + q * 8;
      #pragma unroll
      for (int kt = 0; kt < 8; ++kt) whf[i][kt] = *(const half8*)(ph + kt * 32);
      const f16* pq = wAll + OFF_WHH + ((w + 4*i) * 16 + nl) * 64 + q * 8;
      #pragma unroll
      for (int kt = 0; kt < 2; ++kt) whhf[i][kt] = *(const half8*)(pq + kt * 32);
    }
    const f16* pd = wAll + OFF_WD + (w * 16 + nl) * 64 + q * 8;
    #pragma unroll
    for (int kt = 0; kt < 2; ++kt) wdf[kt] = *(const half8*)(pd + kt * 32);
  }

  float wib[4], vdb[16], ebs[16], wdb[4];
  #pragma unroll
  for (int r = 0; r < 4; ++r) { wib[r] = Wi_b[d0 + r]; wdb[r] = Wd_b[d0 + r]; }
  #pragma unroll
  for (int i = 0; i < 4; ++i)
    #pragma unroll
    for (int r = 0; r < 4; ++r) {
      vdb[i*4+r] = Vd_b[(w + 4*i) * 16 + q * 4 + r];
      ebs[i*4+r] = ebih[i * 64 + d0 + r] + ebhh[i * 64 + d0 + r];
    }

  for (int i = tid; i < BT * HS; i += 256) { Hl[i] = (f16)0.f; Cl[i] = (f16)0.f; }
  for (int i = tid; i < T_TOT; i += 256) {
    float v;
    if      (i < T_W) v = e_h[i];
    else if (i < T_M) v = e_w[i - T_W];
    else if (i < T_Y) v = e_m[i - T_M];
    else              v = e_y[i - T_Y];
    Tl[i] = v;
  }
  float creg[2][4];
  #pragma unroll
  for (int bt = 0; bt < 2; ++bt)
    #pragma unroll
    for (int r = 0; r < 4; ++r) creg[bt][r] = 0.f;
  bar_lds();

  for (int t = 0; t < LEN; ++t) {
    #pragma unroll
    for (int bb = 0; bb < BT; ++bb) {
      float v;
      if (tid < PQN) v = __uint_as_float(pf[bb]);
      else           v = Tl[tbase + (int)pf[bb] * twid + tsub];
      Xl[bb * XS + tid] = (f16)v;
    }
    if (t + 1 < LEN) {
      const u32* pp = pptr + (size_t)(t + 1) * tstr;
      #pragma unroll
      for (int bb = 0; bb < BT; ++bb) pf[bb] = pp[(size_t)bb * pstr];
    }
    bar_lds();

    #pragma unroll
    for (int bt = 0; bt < 2; ++bt) {
      const int row = bt * 16 + nl;
      f32x4 acc = {0.f, 0.f, 0.f, 0.f};
      const f16* xb = &Xl[row * XS + q * 8];
      #pragma unroll
      for (int kt = 0; kt < 8; ++kt)
        acc = __builtin_amdgcn_mfma_f32_16x16x32_f16(wif[kt], *(const half8*)(xb + kt * 32), acc, 0, 0, 0);
      const f16* hb = &Hl[row * HS + q * 8];
      const f16* cb = &Cl[row * HS + q * 8];
      half8 h0 = *(const half8*)hb, h1 = *(const half8*)(hb + 32);
      half8 c0 = *(const half8*)cb, c1 = *(const half8*)(cb + 32);
      acc = __builtin_amdgcn_mfma_f32_16x16x32_f16(wef[0], h0, acc, 0, 0, 0);
      acc = __builtin_amdgcn_mfma_f32_16x16x32_f16(wef[1], h1, acc, 0, 0, 0);
      acc = __builtin_amdgcn_mfma_f32_16x16x32_f16(wef[2], c0, acc, 0, 0, 0);
      acc = __builtin_amdgcn_mfma_f32_16x16x32_f16(wef[3], c1, acc, 0, 0, 0);
      f16x4 uv;
      #pragma unroll
      for (int r = 0; r < 4; ++r) uv[r] = (f16)tanhf_(acc[r] + wib[r]);
      *(f16x4*)(&Ul[row * HS + d0]) = uv;
      if (t > 0) {
        f32x4 aw = {0.f, 0.f, 0.f, 0.f};
        aw = __builtin_amdgcn_mfma_f32_16x16x32_f16(wdf[0], h0, aw, 0, 0, 0);
        aw = __builtin_amdgcn_mfma_f32_16x16x32_f16(wdf[1], h1, aw, 0, 0, 0);
        f16x4 wv;
        #pragma unroll
        for (int r = 0; r < 4; ++r) wv[r] = (f16)(aw[r] + wdb[r]);
        *(f16x4*)(&wmid[((size_t)(b0 + row) * LEN + (t - 1)) * HN + d0]) = wv;
      }
    }
    bar_lds();

    #pragma unroll
    for (int bt = 0; bt < 2; ++bt) {
      const int row = bt * 16 + nl;
      const f16* ub = &Ul[row * HS + q * 8];
      half8 u0 = *(const half8*)ub, u1 = *(const half8*)(ub + 32);
      float ee[16];
      #pragma unroll
      for (int i = 0; i < 4; ++i) {
        f32x4 acc = {0.f, 0.f, 0.f, 0.f};
        acc = __builtin_amdgcn_mfma_f32_16x16x32_f16(vdf[i][0], u0, acc, 0, 0, 0);
        acc = __builtin_amdgcn_mfma_f32_16x16x32_f16(vdf[i][1], u1, acc, 0, 0, 0);
        #pragma unroll
        for (int r = 0; r < 4; ++r)
          ee[i*4+r] = exp2f((acc[r] + vdb[i*4+r]) * 1.44269504f);
      }
      float s = 0.f;
      #pragma unroll
      for (int j = 0; j < 16; ++j) s += ee[j];
      s += __shfl_xor(s, 16, 64);
      s += __shfl_xor(s, 32, 64);
      if (lane < 16) Sred[bt * 64 + w * 16 + lane] = s;
      #pragma unroll
      for (int i = 0; i < 4; ++i) {
        const int k = (w + 4*i) * 16 + q * 4;
        f16x4 xv = *(const f16x4*)(&Xl[row * XS + k]);
        f16x4 pv;
        #pragma unroll
        for (int r = 0; r < 4; ++r) pv[r] = (f16)((float)xv[r] * ee[i*4+r]);
        *(f16x4*)(&Xl[row * XS + k]) = pv;
      }
    }
    bar_lds();

    f16x4 hstash[2], cstash[2];
    #pragma unroll
    for (int bt = 0; bt < 2; ++bt) {
      const int row = bt * 16 + nl;
      f32x4 g[4], gh[4];
      #pragma unroll
      for (int i = 0; i < 4; ++i) {
        g[i]  = (f32x4){0.f, 0.f, 0.f, 0.f};
        gh[i] = (f32x4){0.f, 0.f, 0.f, 0.f};
      }
      const f16* pb = &Xl[row * XS + q * 8];
      #pragma unroll
      for (int kt = 0; kt < 8; ++kt) {
        half8 bv = *(const half8*)(pb + kt * 32);
        #pragma unroll
        for (int i = 0; i < 4; ++i)
          g[i] = __builtin_amdgcn_mfma_f32_16x16x32_f16(whf[i][kt], bv, g[i], 0, 0, 0);
      }
      const f16* hb = &Hl[row * HS + q * 8];
      half8 h0 = *(const half8*)hb, h1 = *(const half8*)(hb + 32);
      #pragma unroll
      for (int i = 0; i < 4; ++i) {
        gh[i] = __builtin_amdgcn_mfma_f32_16x16x32_f16(whhf[i][0], h0, gh[i], 0, 0, 0);
        gh[i] = __builtin_amdgcn_mfma_f32_16x16x32_f16(whhf[i][1], h1, gh[i], 0, 0, 0);
      }
      const float inv = rcp_(Sred[bt*64 + nl]      + Sred[bt*64 + 16 + nl]
                           + Sred[bt*64 + 32 + nl] + Sred[bt*64 + 48 + nl]);
      f16x4 hv, cv;
      #pragma unroll
      for (int r = 0; r < 4; ++r) {
        const float gi = g[0][r] * inv + gh[0][r] + ebs[0  + r];
        const float gf = g[1][r] * inv + gh[1][r] + ebs[4  + r];
        const float gg = g[2][r] * inv + gh[2][r] + ebs[8  + r];
        const float go = g[3][r] * inv + gh[3][r] + ebs[12 + r];
        float c = sigm(gf) * creg[bt][r] + sigm(gi) * tanhf_(gg);
        creg[bt][r] = c;
        const float h = sigm(go) * tanhf_(c);
        hv[r] = (f16)h; cv[r] = (f16)c;
      }
      hstash[bt] = hv; cstash[bt] = cv;
      *(f16x4*)(&mid[((size_t)(b0 + row) * LEN + t) * HN + d0]) = hv;
    }
    bar_lds();
    #pragma unroll
    for (int bt = 0; bt < 2; ++bt) {
      const int row = bt * 16 + nl;
      *(f16x4*)(&Hl[row * HS + d0]) = hstash[bt];
      *(f16x4*)(&Cl[row * HS + d0]) = cstash[bt];
    }
  }

  bar_lds();
  #pragma unroll
  for (int bt = 0; bt < 2; ++bt) {
    const int row = bt * 16 + nl;
    const f16* hb = &Hl[row * HS + q * 8];
    half8 h0 = *(const half8*)hb, h1 = *(const half8*)(hb + 32);
    f32x4 aw = {0.f, 0.f, 0.f, 0.f};
    aw = __builtin_amdgcn_mfma_f32_16x16x32_f16(wdf[0], h0, aw, 0, 0, 0);
    aw = __builtin_amdgcn_mfma_f32_16x16x32_f16(wdf[1], h1, aw, 0, 0, 0);
    f16x4 wv;
    #pragma unroll
    for (int r = 0; r < 4; ++r) wv[r] = (f16)(aw[r] + wdb[r]);
    *(f16x4*)(&wmid[((size_t)(b0 + row) * LEN + (LEN - 1)) * HN + d0]) = wv;
  }
}

// ---------------- decoder v3: wm rows register-resident, tiny LDS ----------
// lane t owns wm[t][0..63] in 32 VGPRs (no wml LDS -> no bank conflicts, no
// LDS occupancy cap).  gates via M4 reassociation as before.
__global__ __launch_bounds__(512) void dec_kernel(
    const f16* __restrict__ mids,     // cols 0..63 at stride MS per (b,t)
    const f16* __restrict__ wms,      // cols 0..63 at stride MS per (b,t)
    const int MS,
    const float* __restrict__ lblp,
    const float* __restrict__ Wd2_w,  // (64,2)
    const float* __restrict__ Vdt_w,  // (1,64)
    const float* __restrict__ Vdt_b,  // (1)
    const float* __restrict__ dWih,   // (4,65)
    const float* __restrict__ dWhh,   // (4,1)
    const float* __restrict__ dbih, const float* __restrict__ dbhh,
    float* __restrict__ out)          // (B,LD)
{
  __shared__ __attribute__((aligned(16))) float qv[DW][HN];
  __shared__ __attribute__((aligned(16))) float vs[HN];
  __shared__ __attribute__((aligned(16))) float ws4[4 * 65];

  const int w    = threadIdx.x >> 6;
  const int lane = threadIdx.x & 63;
  const int b    = blockIdx.x * DW + w;

  if (threadIdx.x < HN)     vs[threadIdx.x]  = Vdt_w[threadIdx.x];
  if (threadIdx.x < 4 * 65) ws4[threadIdx.x] = dWih[threadIdx.x];

  // wm row -> registers (lane = t)
  half8 wmr[8];
  if (lane < LEN) {
    const f16* p = wms + ((size_t)b * LEN + lane) * MS;
    #pragma unroll
    for (int k = 0; k < 8; ++k) wmr[k] = *(const half8*)(p + k * 8);
  } else {
    #pragma unroll
    for (int k = 0; k < 8; ++k)
      #pragma unroll
      for (int e = 0; e < 8; ++e) wmr[k][e] = (f16)0.f;
  }
  __syncthreads();   // vs/ws4 visible

  // M4 precompute in registers: lane = t
  float macc[4] = {0.f, 0.f, 0.f, 0.f};
  if (lane < LEN) {
    const f16* mrow = mids + ((size_t)b * LEN + lane) * MS;
    #pragma unroll
    for (int k8 = 0; k8 < 8; ++k8) {
      half8 mv = *(const half8*)(mrow + k8 * 8);
      #pragma unroll
      for (int e = 0; e < 8; ++e) {
        const float m = (float)mv[e];
        #pragma unroll
        for (int j = 0; j < 4; ++j) macc[j] += ws4[j * 65 + k8 * 8 + e] * m;
      }
    }
  }

  const float dpin = lblp[b * LEN + (LEN - 1)];
  const float w20 = Wd2_w[2 * lane];
  const float w21 = Wd2_w[2 * lane + 1];
  const float vdtb = Vdt_b[0];
  float wxx[4], whh4[4], bb4[4];
  #pragma unroll
  for (int j = 0; j < 4; ++j) {
    wxx[j]  = dWih[j * 65 + 64];
    whh4[j] = dWhh[j];
    bb4[j]  = dbih[j] + dbhh[j];
  }

  float hi = 0.0f, ci = 0.0f;
  for (int s = 0; s < LDN; ++s) {
    qv[w][lane] = w20 * hi + w21 * ci;   // same-wave LDS RAW: compiler waits

    float p0 = 0.f, p1 = 0.f, p2 = 0.f, p3 = 0.f;
    if (lane < LEN) {
      float acc = 0.f;
      #pragma unroll
      for (int k8 = 0; k8 < 8; ++k8) {
        float4 qa = *(const float4*)&qv[w][k8 * 8];
        float4 qb = *(const float4*)&qv[w][k8 * 8 + 4];
        float4 va = *(const float4*)&vs[k8 * 8];
        float4 vb = *(const float4*)&vs[k8 * 8 + 4];
        half8 wv = wmr[k8];
        acc += tanhf_(qa.x + (float)wv[0]) * va.x
             + tanhf_(qa.y + (float)wv[1]) * va.y
             + tanhf_(qa.z + (float)wv[2]) * va.z
             + tanhf_(qa.w + (float)wv[3]) * va.w
             + tanhf_(qb.x + (float)wv[4]) * vb.x
             + tanhf_(qb.y + (float)wv[5]) * vb.y
             + tanhf_(qb.z + (float)wv[6]) * vb.z
             + tanhf_(qb.w + (float)wv[7]) * vb.w;
      }
      const float score = acc + vdtb;
      p0 = score * macc[0]; p1 = score * macc[1];
      p2 = score * macc[2]; p3 = score * macc[3];
    }
    #pragma unroll
    for (int off = 32; off >= 1; off >>= 1) {
      p0 += __shfl_xor(p0, off, 64);
      p1 += __shfl_xor(p1, off, 64);
      p2 += __shfl_xor(p2, off, 64);
      p3 += __shfl_xor(p3, off, 64);
    }
    const float g0 = p0 + wxx[0] * dpin + bb4[0] + whh4[0] * hi;
    const float g1 = p1 + wxx[1] * dpin + bb4[1] + whh4[1] * hi;
    const float g2 = p2 + wxx[2] * dpin + bb4[2] + whh4[2] * hi;
    const float g3 = p3 + wxx[3] * dpin + bb4[3] + whh4[3] * hi;
    ci = sigm(g1) * ci + sigm(g0) * tanhf_(g2);
    hi = sigm(g3) * tanhf_(ci);
    if (lane == 0) out[b * LDN + s] = hi;
  }
}

extern "C" void kernel_launch(void* const* d_in, const int* in_sizes, int n_in,
                              void* d_out, int out_size, void* d_ws, size_t ws_size,
                              hipStream_t stream) {
  (void)in_sizes; (void)n_in; (void)out_size;
  const float* ipq   = (const float*)d_in[0];
  const float* lblp  = (const float*)d_in[1];
  const float* e_h   = (const float*)d_in[2];
  const float* e_w   = (const float*)d_in[3];
  const float* e_m   = (const float*)d_in[4];
  const float* e_y   = (const float*)d_in[5];
  const float* Wi_w  = (const float*)d_in[6];
  const float* Wi_b  = (const float*)d_in[7];
  const float* We_w  = (const float*)d_in[8];
  const float* Vd_w  = (const float*)d_in[9];
  const float* Vd_b  = (const float*)d_in[10];
  const float* eWih  = (const float*)d_in[11];
  const float* eWhh  = (const float*)d_in[12];
  const float* ebih  = (const float*)d_in[13];
  const float* ebhh  = (const float*)d_in[14];
  const float* Wd_w  = (const float*)d_in[15];
  const float* Wd_b  = (const float*)d_in[16];
  const float* Wd2_w = (const float*)d_in[17];
  const float* Vdt_w = (const float*)d_in[18];
  const float* Vdt_b = (const float*)d_in[19];
  const float* dWih  = (const float*)d_in[20];
  const float* dWhh  = (const float*)d_in[21];
  const float* dbih  = (const float*)d_in[22];
  const float* dbhh  = (const float*)d_in[23];
  const int* itime   = (const int*)d_in[24];
  float* out = (float*)d_out;

  const size_t xpreB = (size_t)BB * LEN * XPS * 2;   // 167.77 MB
  const size_t wcvtB = (size_t)W_TOTAL * 2;          // 254 KB

  if (ws_size >= xpreB + wcvtB) {
    f16* xpre = (f16*)d_ws;
    f16* wcvt = (f16*)((char*)d_ws + xpreB);
    prep_all<<<dim3(PREP_BLOCKS + CONV_BLOCKS), dim3(256), 0, stream>>>(
        ipq, e_h, e_w, e_m, e_y, itime, xpre,
        Wi_w, We_w, Vd_w, eWih, eWhh, Wd_w, wcvt);
    enc_x<<<dim3(ENC_BLOCKS), dim3(256), 0, stream>>>(
        xpre, Wi_b, Vd_b, ebih, ebhh, Wd_b, wcvt, xpre);
    dec_kernel<<<dim3(DEC_BLOCKS), dim3(512), 0, stream>>>(
        xpre, xpre + 64, XPS, lblp, Wd2_w, Vdt_w, Vdt_b,
        dWih, dWhh, dbih, dbhh, out);
  } else {
    const size_t midB = (size_t)BB * LEN * HN * 2;   // 41.94 MB
    f16* mid  = (f16*)d_ws;
    f16* wmid = (f16*)((char*)d_ws + midB);
    f16* wcvt = (f16*)((char*)d_ws + 2 * midB);
    conv_w<<<dim3(CONV_BLOCKS), dim3(256), 0, stream>>>(
        Wi_w, We_w, Vd_w, eWih, eWhh, Wd_w, wcvt);
    enc_fb<<<dim3(ENC_BLOCKS), dim3(256), 0, stream>>>(
        ipq, e_h, e_w, e_m, e_y, Wi_b, Vd_b, ebih, ebhh, Wd_b, wcvt, itime,
        mid, wmid);
    dec_kernel<<<dim3(DEC_BLOCKS), dim3(512), 0, stream>>>(
        mid, wmid, HN, lblp, Wd2_w, Vdt_w, Vdt_b,
        dWih, dWhh, dbih, dbhh, out);
  }
}